// Round 2
// baseline (724.295 us; speedup 1.0000x reference)
//
#include <hip/hip_runtime.h>
#include <hip/hip_bf16.h>
#include <math.h>

// Shapes: B=2, S=2048, H=1024, nh=16, hd=64. Inputs f32, outputs f32.
// d_out = [out: 2*2048*1024] ++ [attn: 2*16*2048*2048], both f32.
// Internals (q_rope/k_rope/v/o_buf) are bf16 for MFMA.

typedef __attribute__((ext_vector_type(8))) short bx8;   // 8 bf16 (4 VGPRs)
typedef __attribute__((ext_vector_type(4))) float fx4;   // MFMA accum
typedef __attribute__((ext_vector_type(4))) float f4v;

#define MFMA_BF16(a, b, c) __builtin_amdgcn_mfma_f32_16x16x32_bf16(a, b, c, 0, 0, 0)

__device__ __forceinline__ short f2bf(float f) {
    union { float f; unsigned u; } v; v.f = f;
    unsigned u = v.u;
    u += 0x7fffu + ((u >> 16) & 1u);   // RTNE
    return (short)(u >> 16);
}

__device__ __forceinline__ bx8 pack8(f4v a, f4v b) {
    bx8 r;
    r[0] = f2bf(a[0]); r[1] = f2bf(a[1]); r[2] = f2bf(a[2]); r[3] = f2bf(a[3]);
    r[4] = f2bf(b[0]); r[5] = f2bf(b[1]); r[6] = f2bf(b[2]); r[7] = f2bf(b[3]);
    return r;
}

// ---------------- RoPE cos/sin table: [2048][64] f32 each ----------------
__global__ void rope_table_kernel(float* __restrict__ cosT, float* __restrict__ sinT) {
    int i = blockIdx.x * 256 + threadIdx.x;
    if (i >= 2048 * 64) return;
    int s = i >> 6, d = i & 63;
    int fi = d & 31;                               // emb = concat(freqs, freqs)
    float inv_freq = powf(10000.0f, -(float)fi / 32.0f);
    float ang = (float)s * inv_freq;
    cosT[i] = cosf(ang);
    sinT[i] = sinf(ang);
}

// ---------------- GEMM: C[M=4096][N=1024] = A[4096][1024] @ W[1024][1024]^T
// BM=128, BN=64, BK=32, 256 threads (4 waves stacked on M, each 32x64).
// MODE 0: RoPE + 0.125 scale, write q_rope[bh][s][d] bf16
// MODE 1: RoPE, write k_rope        MODE 2: plain, write v[bh][s][d] bf16
// MODE 3: A is bf16 (o_buf), plain, write out[r][c] row-major FLOAT32
template<int MODE>
__global__ __launch_bounds__(256) void gemm_kernel(
        const void* __restrict__ Aptr, const float* __restrict__ W,
        const float* __restrict__ cosT, const float* __restrict__ sinT,
        void* __restrict__ Out)
{
    __shared__ short As[128][40];   // +8 pad: 80B row stride, 16B-aligned
    __shared__ short Bs[64][40];
    const int bm = blockIdx.x, bn = blockIdx.y;
    const int tid = threadIdx.x;
    const int wave = tid >> 6, lane = tid & 63;
    const int cl = lane & 15, lg = lane >> 4;

    fx4 acc[2][4];
    #pragma unroll
    for (int m = 0; m < 2; m++)
        #pragma unroll
        for (int n = 0; n < 4; n++) acc[m][n] = (fx4){0.f, 0.f, 0.f, 0.f};

    const int arow = tid >> 1, acol = (tid & 1) * 16;   // A: 128 rows x 32 cols
    const int brow = tid >> 2, bcol = (tid & 3) * 8;    // B: 64 rows x 32 cols

    for (int k0 = 0; k0 < 1024; k0 += 32) {
        if constexpr (MODE == 3) {
            const short* ga = (const short*)Aptr + (size_t)(bm * 128 + arow) * 1024 + k0 + acol;
            bx8 s0 = *(const bx8*)ga;
            bx8 s1 = *(const bx8*)(ga + 8);
            *(bx8*)&As[arow][acol]     = s0;
            *(bx8*)&As[arow][acol + 8] = s1;
        } else {
            const float* ga = (const float*)Aptr + (size_t)(bm * 128 + arow) * 1024 + k0 + acol;
            f4v a0 = *(const f4v*)ga,       a1 = *(const f4v*)(ga + 4);
            f4v a2 = *(const f4v*)(ga + 8), a3 = *(const f4v*)(ga + 12);
            *(bx8*)&As[arow][acol]     = pack8(a0, a1);
            *(bx8*)&As[arow][acol + 8] = pack8(a2, a3);
        }
        {
            const float* gb = W + (size_t)(bn * 64 + brow) * 1024 + k0 + bcol;
            f4v b0 = *(const f4v*)gb, b1 = *(const f4v*)(gb + 4);
            *(bx8*)&Bs[brow][bcol] = pack8(b0, b1);
        }
        __syncthreads();
        bx8 af[2], bf[4];
        #pragma unroll
        for (int m = 0; m < 2; m++) af[m] = *(const bx8*)&As[wave * 32 + m * 16 + cl][lg * 8];
        #pragma unroll
        for (int n = 0; n < 4; n++) bf[n] = *(const bx8*)&Bs[n * 16 + cl][lg * 8];
        #pragma unroll
        for (int m = 0; m < 2; m++)
            #pragma unroll
            for (int n = 0; n < 4; n++)
                acc[m][n] = MFMA_BF16(af[m], bf[n], acc[m][n]);
        __syncthreads();
    }

    // epilogue: C row = bm*128 + wave*32 + m*16 + lg*4 + reg ; col = bn*64 + n*16 + cl
    const int rbase = bm * 128 + wave * 32 + (lg << 2);
    #pragma unroll
    for (int m = 0; m < 2; m++) {
        #pragma unroll
        for (int reg = 0; reg < 4; reg++) {
            const int r = rbase + m * 16 + reg;
            const int b = r >> 11, s = r & 2047;
            #pragma unroll
            for (int n = 0; n < 4; n++) {
                const int d = n * 16 + cl;          // BN=64 => head h = bn, dim = d
                float v = acc[m][n][reg];
                if constexpr (MODE == 0 || MODE == 1) {
                    const float cs = cosT[s * 64 + d], sn = sinT[s * 64 + d];
                    const float partner = acc[m][n ^ 2][reg];   // d ^ 32 lives in frag n^2
                    const float rot = (d < 32) ? -partner : partner;
                    v = v * cs + rot * sn;
                    if constexpr (MODE == 0) v *= 0.125f;       // 1/sqrt(hd) folded into q
                    ((short*)Out)[(size_t)((b * 16 + bn) * 2048 + s) * 64 + d] = f2bf(v);
                } else if constexpr (MODE == 2) {
                    ((short*)Out)[(size_t)((b * 16 + bn) * 2048 + s) * 64 + d] = f2bf(v);
                } else {
                    ((float*)Out)[(size_t)r * 1024 + bn * 64 + d] = v;
                }
            }
        }
    }
}

// ---------------- Attention: one block per (qt, h, b); 4 waves, 16 q-rows each.
// Pass A: online row max/sum over causal k-tiles (scores = q.k + bias).
// Pass B: recompute scores, P = exp(s-m)/l -> f32 attn out (direct from regs),
//         bf16 P tile in LDS -> O += P @ V (V transposed into LDS).
// Then zero-fill k > q tiles with f32 zeros.
__global__ __launch_bounds__(256) void attn_kernel(
        const short* __restrict__ Q, const short* __restrict__ K,
        const short* __restrict__ V, const float* __restrict__ bias,
        float* __restrict__ attn_out, short* __restrict__ o_buf)
{
    const int S = 2048;
    const int qt = blockIdx.x, h = blockIdx.y, b = blockIdx.z;
    const int bh = b * 16 + h;
    const int tid = threadIdx.x, wave = tid >> 6, lane = tid & 63;
    const int cl = lane & 15, lg = lane >> 4;
    const size_t base = (size_t)bh * S * 64;

    __shared__ short Vt[64][72];       // V^T tile: [d][k], padded
    __shared__ short P[4][16][72];     // per-wave P tile: [qrow][k], padded

    // Q fragments held in registers (A-operand: row=cl, k=lg*8+j)
    bx8 qf[2];
    {
        const short* qp = Q + base + (size_t)(qt * 64 + wave * 16 + cl) * 64 + lg * 8;
        qf[0] = *(const bx8*)qp;
        qf[1] = *(const bx8*)(qp + 32);
    }
    const int q0 = qt * 64 + wave * 16 + (lg << 2);   // first of this lane's 4 q rows

    float mrow[4], lrow[4];
    #pragma unroll
    for (int i = 0; i < 4; i++) { mrow[i] = -3.0e38f; lrow[i] = 0.f; }

    // ---- PASS A ----
    for (int kt = 0; kt <= qt; ++kt) {
        fx4 sacc[4];
        #pragma unroll
        for (int n = 0; n < 4; n++) sacc[n] = (fx4){0.f, 0.f, 0.f, 0.f};
        #pragma unroll
        for (int n = 0; n < 4; n++) {
            const short* kp = K + base + (size_t)(kt * 64 + n * 16 + cl) * 64 + lg * 8;
            bx8 k0 = *(const bx8*)kp;
            bx8 k1 = *(const bx8*)(kp + 32);
            sacc[n] = MFMA_BF16(qf[0], k0, sacc[n]);
            sacc[n] = MFMA_BF16(qf[1], k1, sacc[n]);
        }
        #pragma unroll
        for (int reg = 0; reg < 4; reg++) {
            const int qr = q0 + reg;
            float sv[4];
            #pragma unroll
            for (int n = 0; n < 4; n++) {
                const int kc = kt * 64 + n * 16 + cl;
                sv[n] = (kc <= qr) ? (sacc[n][reg] + bias[(size_t)qr * 2048 + kc]) : -3.0e38f;
            }
            float tmax = fmaxf(fmaxf(sv[0], sv[1]), fmaxf(sv[2], sv[3]));
            #pragma unroll
            for (int off = 1; off < 16; off <<= 1) tmax = fmaxf(tmax, __shfl_xor(tmax, off));
            const float mnew = fmaxf(mrow[reg], tmax);
            float sum = __expf(sv[0] - mnew) + __expf(sv[1] - mnew) +
                        __expf(sv[2] - mnew) + __expf(sv[3] - mnew);
            #pragma unroll
            for (int off = 1; off < 16; off <<= 1) sum += __shfl_xor(sum, off);
            lrow[reg] = lrow[reg] * __expf(mrow[reg] - mnew) + sum;
            mrow[reg] = mnew;
        }
    }
    float invl[4];
    #pragma unroll
    for (int i = 0; i < 4; i++) invl[i] = 1.0f / lrow[i];

    fx4 oacc[4];
    #pragma unroll
    for (int n = 0; n < 4; n++) oacc[n] = (fx4){0.f, 0.f, 0.f, 0.f};

    // ---- PASS B ----
    for (int kt = 0; kt <= qt; ++kt) {
        __syncthreads();                       // protect Vt from previous iteration's readers
        {   // stage V^T: thread -> row kr = tid>>2, d0 = (tid&3)*16, 16 elems
            const int kr = tid >> 2, d0 = (tid & 3) * 16;
            const short* vp = V + base + (size_t)(kt * 64 + kr) * 64 + d0;
            bx8 v0 = *(const bx8*)vp;
            bx8 v1 = *(const bx8*)(vp + 8);
            #pragma unroll
            for (int j = 0; j < 8; j++) Vt[d0 + j][kr] = v0[j];
            #pragma unroll
            for (int j = 0; j < 8; j++) Vt[d0 + 8 + j][kr] = v1[j];
        }
        __syncthreads();

        fx4 sacc[4];
        #pragma unroll
        for (int n = 0; n < 4; n++) sacc[n] = (fx4){0.f, 0.f, 0.f, 0.f};
        #pragma unroll
        for (int n = 0; n < 4; n++) {
            const short* kp = K + base + (size_t)(kt * 64 + n * 16 + cl) * 64 + lg * 8;
            bx8 k0 = *(const bx8*)kp;
            bx8 k1 = *(const bx8*)(kp + 32);
            sacc[n] = MFMA_BF16(qf[0], k0, sacc[n]);
            sacc[n] = MFMA_BF16(qf[1], k1, sacc[n]);
        }
        #pragma unroll
        for (int reg = 0; reg < 4; reg++) {
            const int qr = q0 + reg;
            #pragma unroll
            for (int n = 0; n < 4; n++) {
                const int kc = kt * 64 + n * 16 + cl;
                const float sv = (kc <= qr) ? (sacc[n][reg] + bias[(size_t)qr * 2048 + kc])
                                            : -3.0e38f;
                const float p = __expf(sv - mrow[reg]) * invl[reg];
                P[wave][(lg << 2) + reg][n * 16 + cl] = f2bf(p);
                attn_out[((size_t)bh * S + qr) * S + kc] = p;   // f32, masked -> exact 0
            }
        }
        // PV: O[q][d] += P[q][k] * V[k][d]
        #pragma unroll
        for (int kk = 0; kk < 2; ++kk) {
            bx8 pa = *(const bx8*)&P[wave][cl][kk * 32 + lg * 8];
            #pragma unroll
            for (int n = 0; n < 4; n++) {
                bx8 vb = *(const bx8*)&Vt[n * 16 + cl][kk * 32 + lg * 8];
                oacc[n] = MFMA_BF16(pa, vb, oacc[n]);
            }
        }
    }

    // write O tile to o_buf[b][s][h*64+d] (bf16)
    #pragma unroll
    for (int reg = 0; reg < 4; reg++) {
        const int sq = q0 + reg;
        #pragma unroll
        for (int n = 0; n < 4; n++) {
            const int d = n * 16 + cl;
            o_buf[(size_t)(b * 2048 + sq) * 1024 + h * 64 + d] = f2bf(oacc[n][reg]);
        }
    }

    // zero-fill the strict upper triangle tiles (k >= (qt+1)*64) for these 64 q rows
    const int c0 = (qt + 1) * 64;
    if (c0 < S) {
        const int count = S - c0;          // multiple of 64
        const int total = 64 * count;
        const f4v z = (f4v){0.f, 0.f, 0.f, 0.f};
        for (int i = tid * 4; i < total; i += 1024) {   // 256 threads * 4 floats
            const int row = i / count;
            const int cc = c0 + (i % count);
            *(f4v*)(attn_out + ((size_t)bh * S + qt * 64 + row) * S + cc) = z;
        }
    }
}

extern "C" void kernel_launch(void* const* d_in, const int* in_sizes, int n_in,
                              void* d_out, int out_size, void* d_ws, size_t ws_size,
                              hipStream_t stream) {
    const float* x    = (const float*)d_in[0];
    const float* Wq   = (const float*)d_in[1];
    const float* Wk   = (const float*)d_in[2];
    const float* Wv   = (const float*)d_in[3];
    const float* Wo   = (const float*)d_in[4];
    const float* bias = (const float*)d_in[5];

    float* out  = (float*)d_out;                       // [2,2048,1024] f32
    float* attn = out + (size_t)2 * 2048 * 1024;       // [2,16,2048,2048] f32

    char* ws = (char*)d_ws;
    float* cosT = (float*)ws;                          // 2048*64 f32
    float* sinT = cosT + 2048 * 64;
    short* q_rope = (short*)(ws + (size_t)2 * 2048 * 64 * 4);   // 1 MiB offset
    short* k_rope = q_rope + (size_t)32 * 2048 * 64;
    short* v_bf   = k_rope + (size_t)32 * 2048 * 64;
    short* o_buf  = v_bf   + (size_t)32 * 2048 * 64;

    rope_table_kernel<<<512, 256, 0, stream>>>(cosT, sinT);
    dim3 g(32, 16);
    gemm_kernel<0><<<g, 256, 0, stream>>>(x, Wq, cosT, sinT, q_rope);
    gemm_kernel<1><<<g, 256, 0, stream>>>(x, Wk, cosT, sinT, k_rope);
    gemm_kernel<2><<<g, 256, 0, stream>>>(x, Wv, cosT, sinT, v_bf);
    attn_kernel<<<dim3(32, 16, 2), 256, 0, stream>>>(q_rope, k_rope, v_bf, bias, attn, o_buf);
    gemm_kernel<3><<<g, 256, 0, stream>>>(o_buf, Wo, cosT, sinT, out);
}

// Round 3
// 503.375 us; speedup vs baseline: 1.4389x; 1.4389x over previous
//
#include <hip/hip_runtime.h>
#include <hip/hip_bf16.h>
#include <math.h>

// Shapes: B=2, S=2048, H=1024, nh=16, hd=64. Inputs f32, outputs f32.
// d_out = [out: 2*2048*1024] ++ [attn: 2*16*2048*2048], both f32.
// Internals (q_rope/k_rope/v/o_buf) are bf16 for MFMA.

typedef __attribute__((ext_vector_type(8))) short bx8;   // 8 bf16 (4 VGPRs)
typedef __attribute__((ext_vector_type(4))) float fx4;   // MFMA accum
typedef __attribute__((ext_vector_type(4))) float f4v;

#define MFMA_BF16(a, b, c) __builtin_amdgcn_mfma_f32_16x16x32_bf16(a, b, c, 0, 0, 0)

__device__ __forceinline__ short f2bf(float f) {
    union { float f; unsigned u; } v; v.f = f;
    unsigned u = v.u;
    u += 0x7fffu + ((u >> 16) & 1u);   // RTNE
    return (short)(u >> 16);
}
__device__ __forceinline__ float bf2f(short s) {
    union { unsigned u; float f; } v; v.u = ((unsigned)(unsigned short)s) << 16;
    return v.f;
}

__device__ __forceinline__ bx8 pack8(f4v a, f4v b) {
    bx8 r;
    r[0] = f2bf(a[0]); r[1] = f2bf(a[1]); r[2] = f2bf(a[2]); r[3] = f2bf(a[3]);
    r[4] = f2bf(b[0]); r[5] = f2bf(b[1]); r[6] = f2bf(b[2]); r[7] = f2bf(b[3]);
    return r;
}

// ---------------- RoPE cos/sin table: [2048][64] f32 each ----------------
__global__ void rope_table_kernel(float* __restrict__ cosT, float* __restrict__ sinT) {
    int i = blockIdx.x * 256 + threadIdx.x;
    if (i >= 2048 * 64) return;
    int s = i >> 6, d = i & 63;
    int fi = d & 31;                               // emb = concat(freqs, freqs)
    float inv_freq = powf(10000.0f, -(float)fi / 32.0f);
    float ang = (float)s * inv_freq;
    cosT[i] = cosf(ang);
    sinT[i] = sinf(ang);
}

// ---------------- GEMM: C[M=4096][N=1024] = A[4096][1024] @ W[1024][1024]^T
// BM=128, BN=64, BK=32, 256 threads (4 waves stacked on M, each 32x64).
// MODE 0: RoPE + 0.125 scale, write q_rope[bh][s][d] bf16
// MODE 1: RoPE, write k_rope        MODE 2: plain, write v[bh][s][d] bf16
// MODE 3: A is bf16 (o_buf), plain, write out[r][c] row-major FLOAT32
template<int MODE>
__global__ __launch_bounds__(256) void gemm_kernel(
        const void* __restrict__ Aptr, const float* __restrict__ W,
        const float* __restrict__ cosT, const float* __restrict__ sinT,
        void* __restrict__ Out)
{
    __shared__ short As[128][40];   // +8 pad: 80B row stride, 16B-aligned
    __shared__ short Bs[64][40];
    const int bm = blockIdx.x, bn = blockIdx.y;
    const int tid = threadIdx.x;
    const int wave = tid >> 6, lane = tid & 63;
    const int cl = lane & 15, lg = lane >> 4;

    fx4 acc[2][4];
    #pragma unroll
    for (int m = 0; m < 2; m++)
        #pragma unroll
        for (int n = 0; n < 4; n++) acc[m][n] = (fx4){0.f, 0.f, 0.f, 0.f};

    const int arow = tid >> 1, acol = (tid & 1) * 16;   // A: 128 rows x 32 cols
    const int brow = tid >> 2, bcol = (tid & 3) * 8;    // B: 64 rows x 32 cols

    for (int k0 = 0; k0 < 1024; k0 += 32) {
        if constexpr (MODE == 3) {
            const short* ga = (const short*)Aptr + (size_t)(bm * 128 + arow) * 1024 + k0 + acol;
            bx8 s0 = *(const bx8*)ga;
            bx8 s1 = *(const bx8*)(ga + 8);
            *(bx8*)&As[arow][acol]     = s0;
            *(bx8*)&As[arow][acol + 8] = s1;
        } else {
            const float* ga = (const float*)Aptr + (size_t)(bm * 128 + arow) * 1024 + k0 + acol;
            f4v a0 = *(const f4v*)ga,       a1 = *(const f4v*)(ga + 4);
            f4v a2 = *(const f4v*)(ga + 8), a3 = *(const f4v*)(ga + 12);
            *(bx8*)&As[arow][acol]     = pack8(a0, a1);
            *(bx8*)&As[arow][acol + 8] = pack8(a2, a3);
        }
        {
            const float* gb = W + (size_t)(bn * 64 + brow) * 1024 + k0 + bcol;
            f4v b0 = *(const f4v*)gb, b1 = *(const f4v*)(gb + 4);
            *(bx8*)&Bs[brow][bcol] = pack8(b0, b1);
        }
        __syncthreads();
        bx8 af[2], bf[4];
        #pragma unroll
        for (int m = 0; m < 2; m++) af[m] = *(const bx8*)&As[wave * 32 + m * 16 + cl][lg * 8];
        #pragma unroll
        for (int n = 0; n < 4; n++) bf[n] = *(const bx8*)&Bs[n * 16 + cl][lg * 8];
        #pragma unroll
        for (int m = 0; m < 2; m++)
            #pragma unroll
            for (int n = 0; n < 4; n++)
                acc[m][n] = MFMA_BF16(af[m], bf[n], acc[m][n]);
        __syncthreads();
    }

    // epilogue: C row = bm*128 + wave*32 + m*16 + lg*4 + reg ; col = bn*64 + n*16 + cl
    const int rbase = bm * 128 + wave * 32 + (lg << 2);
    #pragma unroll
    for (int m = 0; m < 2; m++) {
        #pragma unroll
        for (int reg = 0; reg < 4; reg++) {
            const int r = rbase + m * 16 + reg;
            const int b = r >> 11, s = r & 2047;
            #pragma unroll
            for (int n = 0; n < 4; n++) {
                const int d = n * 16 + cl;          // BN=64 => head h = bn, dim = d
                float v = acc[m][n][reg];
                if constexpr (MODE == 0 || MODE == 1) {
                    const float cs = cosT[s * 64 + d], sn = sinT[s * 64 + d];
                    const float partner = acc[m][n ^ 2][reg];   // d ^ 32 lives in frag n^2
                    const float rot = (d < 32) ? -partner : partner;
                    v = v * cs + rot * sn;
                    if constexpr (MODE == 0) v *= 0.125f;       // 1/sqrt(hd) folded into q
                    ((short*)Out)[(size_t)((b * 16 + bn) * 2048 + s) * 64 + d] = f2bf(v);
                } else if constexpr (MODE == 2) {
                    ((short*)Out)[(size_t)((b * 16 + bn) * 2048 + s) * 64 + d] = f2bf(v);
                } else {
                    ((float*)Out)[(size_t)r * 1024 + bn * 64 + d] = v;
                }
            }
        }
    }
}

// ---------------- Attention ----------------
// Each block handles TWO complementary q-strips (qt, 31-qt) sequentially -> every
// block does exactly 33 k-tiles x 2 passes (load-balanced). 4 waves, 16 q-rows each.
// Per k-tile: bias tile staged in LDS (coalesced f4v); pass B writes attn from
// LDS-staged bf16 P as row-contiguous f4v stores and accumulates O += P@V via MFMA.
__global__ __launch_bounds__(256) void attn_kernel(
        const short* __restrict__ Q, const short* __restrict__ K,
        const short* __restrict__ V, const float* __restrict__ bias,
        float* __restrict__ attn_out, short* __restrict__ o_buf)
{
    const int S = 2048;
    const int h = blockIdx.y, b = blockIdx.z;
    const int bh = b * 16 + h;
    const int tid = threadIdx.x, wave = tid >> 6, lane = tid & 63;
    const int cl = lane & 15, lg = lane >> 4;
    const size_t base = (size_t)bh * S * 64;

    __shared__ float biasT[64][68];    // bias tile, padded (+4)
    __shared__ short Vt[64][72];       // V^T tile: [d][k], padded
    __shared__ short P[4][16][72];     // per-wave P tile: [qrow][k], padded

    for (int sidx = 0; sidx < 2; ++sidx) {
        const int qt = sidx ? (31 - blockIdx.x) : blockIdx.x;

        // Q fragments in registers (A-operand: row=cl, k=lg*8+j)
        bx8 qf[2];
        {
            const short* qp = Q + base + (size_t)(qt * 64 + wave * 16 + cl) * 64 + lg * 8;
            qf[0] = *(const bx8*)qp;
            qf[1] = *(const bx8*)(qp + 32);
        }
        const int q0 = qt * 64 + wave * 16 + (lg << 2);   // first of this lane's 4 q rows
        const int qrl0 = wave * 16 + (lg << 2);           // local row in strip

        float mrow[4], lrow[4];
        #pragma unroll
        for (int i = 0; i < 4; i++) { mrow[i] = -3.0e38f; lrow[i] = 0.f; }

        // ---- PASS A: online row max/sum ----
        for (int kt = 0; kt <= qt; ++kt) {
            __syncthreads();                     // previous LDS readers done
            {   // stage bias tile [64][64] f32, coalesced
                const float* src = bias + (size_t)(qt * 64) * 2048 + kt * 64;
                #pragma unroll
                for (int i = 0; i < 4; ++i) {
                    const int idx = i * 256 + tid;
                    const int row = idx >> 4, c4 = (idx & 15) * 4;
                    *(f4v*)&biasT[row][c4] = *(const f4v*)(src + (size_t)row * 2048 + c4);
                }
            }
            __syncthreads();

            fx4 sacc[4];
            #pragma unroll
            for (int n = 0; n < 4; n++) sacc[n] = (fx4){0.f, 0.f, 0.f, 0.f};
            #pragma unroll
            for (int n = 0; n < 4; n++) {
                const short* kp = K + base + (size_t)(kt * 64 + n * 16 + cl) * 64 + lg * 8;
                bx8 k0 = *(const bx8*)kp;
                bx8 k1 = *(const bx8*)(kp + 32);
                sacc[n] = MFMA_BF16(qf[0], k0, sacc[n]);
                sacc[n] = MFMA_BF16(qf[1], k1, sacc[n]);
            }
            #pragma unroll
            for (int reg = 0; reg < 4; reg++) {
                const int qr = q0 + reg;
                float sv[4];
                #pragma unroll
                for (int n = 0; n < 4; n++) {
                    const int kc = kt * 64 + n * 16 + cl;
                    sv[n] = (kc <= qr) ? (sacc[n][reg] + biasT[qrl0 + reg][n * 16 + cl])
                                       : -3.0e38f;
                }
                float tmax = fmaxf(fmaxf(sv[0], sv[1]), fmaxf(sv[2], sv[3]));
                #pragma unroll
                for (int off = 1; off < 16; off <<= 1) tmax = fmaxf(tmax, __shfl_xor(tmax, off));
                const float mnew = fmaxf(mrow[reg], tmax);
                float sum = __expf(sv[0] - mnew) + __expf(sv[1] - mnew) +
                            __expf(sv[2] - mnew) + __expf(sv[3] - mnew);
                #pragma unroll
                for (int off = 1; off < 16; off <<= 1) sum += __shfl_xor(sum, off);
                lrow[reg] = lrow[reg] * __expf(mrow[reg] - mnew) + sum;
                mrow[reg] = mnew;
            }
        }
        float invl[4];
        #pragma unroll
        for (int i = 0; i < 4; i++) invl[i] = 1.0f / lrow[i];

        fx4 oacc[4];
        #pragma unroll
        for (int n = 0; n < 4; n++) oacc[n] = (fx4){0.f, 0.f, 0.f, 0.f};

        // ---- PASS B: normalized P -> attn (coalesced) + O += P @ V ----
        for (int kt = 0; kt <= qt; ++kt) {
            __syncthreads();                     // previous iteration's readers done
            {   // stage bias tile
                const float* src = bias + (size_t)(qt * 64) * 2048 + kt * 64;
                #pragma unroll
                for (int i = 0; i < 4; ++i) {
                    const int idx = i * 256 + tid;
                    const int row = idx >> 4, c4 = (idx & 15) * 4;
                    *(f4v*)&biasT[row][c4] = *(const f4v*)(src + (size_t)row * 2048 + c4);
                }
            }
            {   // stage V^T: thread -> row kr = tid>>2, d0 = (tid&3)*16, 16 elems
                const int kr = tid >> 2, d0 = (tid & 3) * 16;
                const short* vp = V + base + (size_t)(kt * 64 + kr) * 64 + d0;
                bx8 v0 = *(const bx8*)vp;
                bx8 v1 = *(const bx8*)(vp + 8);
                #pragma unroll
                for (int j = 0; j < 8; j++) Vt[d0 + j][kr] = v0[j];
                #pragma unroll
                for (int j = 0; j < 8; j++) Vt[d0 + 8 + j][kr] = v1[j];
            }
            __syncthreads();

            fx4 sacc[4];
            #pragma unroll
            for (int n = 0; n < 4; n++) sacc[n] = (fx4){0.f, 0.f, 0.f, 0.f};
            #pragma unroll
            for (int n = 0; n < 4; n++) {
                const short* kp = K + base + (size_t)(kt * 64 + n * 16 + cl) * 64 + lg * 8;
                bx8 k0 = *(const bx8*)kp;
                bx8 k1 = *(const bx8*)(kp + 32);
                sacc[n] = MFMA_BF16(qf[0], k0, sacc[n]);
                sacc[n] = MFMA_BF16(qf[1], k1, sacc[n]);
            }
            #pragma unroll
            for (int reg = 0; reg < 4; reg++) {
                const int qr = q0 + reg;
                #pragma unroll
                for (int n = 0; n < 4; n++) {
                    const int kc = kt * 64 + n * 16 + cl;
                    const float sv = (kc <= qr)
                        ? (sacc[n][reg] + biasT[qrl0 + reg][n * 16 + cl]) : -3.0e38f;
                    const float p = __expf(sv - mrow[reg]) * invl[reg];
                    P[wave][qrl0 - wave * 16 + reg][n * 16 + cl] = f2bf(p);
                }
            }
            // coalesced attn write: 4 stores, each = 4 rows x 256B contiguous
            {
                const int rsub = lane >> 4;           // 0..3
                const int c4 = (lane & 15) * 4;
                #pragma unroll
                for (int j = 0; j < 4; ++j) {
                    const int r = 4 * j + rsub;       // local row 0..15 in wave strip
                    const short* ps = &P[wave][r][c4];
                    f4v o;
                    #pragma unroll
                    for (int e = 0; e < 4; ++e) o[e] = bf2f(ps[e]);
                    *(f4v*)(attn_out + ((size_t)bh * S + qt * 64 + wave * 16 + r) * S
                                     + kt * 64 + c4) = o;
                }
            }
            // PV: O[q][d] += P[q][k] * V[k][d]
            #pragma unroll
            for (int kk = 0; kk < 2; ++kk) {
                bx8 pa = *(const bx8*)&P[wave][cl][kk * 32 + lg * 8];
                #pragma unroll
                for (int n = 0; n < 4; n++) {
                    bx8 vb = *(const bx8*)&Vt[n * 16 + cl][kk * 32 + lg * 8];
                    oacc[n] = MFMA_BF16(pa, vb, oacc[n]);
                }
            }
        }

        // write O tile to o_buf[b][s][h*64+d] (bf16)
        #pragma unroll
        for (int reg = 0; reg < 4; reg++) {
            const int sq = q0 + reg;
            #pragma unroll
            for (int n = 0; n < 4; n++) {
                const int d = n * 16 + cl;
                o_buf[(size_t)(b * 2048 + sq) * 1024 + h * 64 + d] = f2bf(oacc[n][reg]);
            }
        }

        // zero-fill the strict upper triangle tiles (k >= (qt+1)*64) for these 64 q rows
        const int c0 = (qt + 1) * 64;
        if (c0 < S) {
            const int count = S - c0;          // multiple of 64
            const int total = 64 * count;
            const f4v z = (f4v){0.f, 0.f, 0.f, 0.f};
            for (int i = tid * 4; i < total; i += 1024) {   // 256 threads * 4 floats
                const int row = i / count;
                const int cc = c0 + (i % count);
                *(f4v*)(attn_out + ((size_t)bh * S + qt * 64 + row) * S + cc) = z;
            }
        }
    }
}

extern "C" void kernel_launch(void* const* d_in, const int* in_sizes, int n_in,
                              void* d_out, int out_size, void* d_ws, size_t ws_size,
                              hipStream_t stream) {
    const float* x    = (const float*)d_in[0];
    const float* Wq   = (const float*)d_in[1];
    const float* Wk   = (const float*)d_in[2];
    const float* Wv   = (const float*)d_in[3];
    const float* Wo   = (const float*)d_in[4];
    const float* bias = (const float*)d_in[5];

    float* out  = (float*)d_out;                       // [2,2048,1024] f32
    float* attn = out + (size_t)2 * 2048 * 1024;       // [2,16,2048,2048] f32

    char* ws = (char*)d_ws;
    float* cosT = (float*)ws;                          // 2048*64 f32
    float* sinT = cosT + 2048 * 64;
    short* q_rope = (short*)(ws + (size_t)2 * 2048 * 64 * 4);   // 1 MiB offset
    short* k_rope = q_rope + (size_t)32 * 2048 * 64;
    short* v_bf   = k_rope + (size_t)32 * 2048 * 64;
    short* o_buf  = v_bf   + (size_t)32 * 2048 * 64;

    rope_table_kernel<<<512, 256, 0, stream>>>(cosT, sinT);
    dim3 g(32, 16);
    gemm_kernel<0><<<g, 256, 0, stream>>>(x, Wq, cosT, sinT, q_rope);
    gemm_kernel<1><<<g, 256, 0, stream>>>(x, Wk, cosT, sinT, k_rope);
    gemm_kernel<2><<<g, 256, 0, stream>>>(x, Wv, cosT, sinT, v_bf);
    attn_kernel<<<dim3(16, 16, 2), 256, 0, stream>>>(q_rope, k_rope, v_bf, bias, attn, o_buf);
    gemm_kernel<3><<<g, 256, 0, stream>>>(o_buf, Wo, cosT, sinT, out);
}

// Round 4
// 408.335 us; speedup vs baseline: 1.7738x; 1.2328x over previous
//
#include <hip/hip_runtime.h>
#include <hip/hip_bf16.h>
#include <math.h>

// Shapes: B=2, S=2048, H=1024, nh=16, hd=64. Inputs f32, outputs f32.
// d_out = [out: 2*2048*1024] ++ [attn: 2*16*2048*2048], both f32.
// Internals (q_rope/k_rope/v/o_buf) are bf16 for MFMA.

typedef __attribute__((ext_vector_type(8))) short bx8;   // 8 bf16 (4 VGPRs)
typedef __attribute__((ext_vector_type(4))) short sx4;   // 4 bf16
typedef __attribute__((ext_vector_type(4))) float fx4;   // MFMA accum
typedef __attribute__((ext_vector_type(4))) float f4v;

#define MFMA_BF16(a, b, c) __builtin_amdgcn_mfma_f32_16x16x32_bf16(a, b, c, 0, 0, 0)

__device__ __forceinline__ short f2bf(float f) {
    union { float f; unsigned u; } v; v.f = f;
    unsigned u = v.u;
    u += 0x7fffu + ((u >> 16) & 1u);   // RTNE
    return (short)(u >> 16);
}

__device__ __forceinline__ bx8 pack8(f4v a, f4v b) {
    bx8 r;
    r[0] = f2bf(a[0]); r[1] = f2bf(a[1]); r[2] = f2bf(a[2]); r[3] = f2bf(a[3]);
    r[4] = f2bf(b[0]); r[5] = f2bf(b[1]); r[6] = f2bf(b[2]); r[7] = f2bf(b[3]);
    return r;
}

// ---------------- RoPE cos/sin table: [2048][64] f32 each ----------------
__global__ void rope_table_kernel(float* __restrict__ cosT, float* __restrict__ sinT) {
    int i = blockIdx.x * 256 + threadIdx.x;
    if (i >= 2048 * 64) return;
    int s = i >> 6, d = i & 63;
    int fi = d & 31;                               // emb = concat(freqs, freqs)
    float inv_freq = powf(10000.0f, -(float)fi / 32.0f);
    float ang = (float)s * inv_freq;
    cosT[i] = cosf(ang);
    sinT[i] = sinf(ang);
}

// ---------------- GEMM: C[M=4096][N=1024] = A[4096][1024] @ W[1024][1024]^T
// BM=128, BN=64, BK=32, 256 threads (4 waves stacked on M, each 32x64).
// MODE 0: RoPE + 0.125 scale, write q_rope[bh][s][d] bf16
// MODE 1: RoPE, write k_rope        MODE 2: plain, write v[bh][s][d] bf16
// MODE 3: A is bf16 (o_buf), plain, write out[r][c] row-major FLOAT32
template<int MODE>
__global__ __launch_bounds__(256) void gemm_kernel(
        const void* __restrict__ Aptr, const float* __restrict__ W,
        const float* __restrict__ cosT, const float* __restrict__ sinT,
        void* __restrict__ Out)
{
    __shared__ short As[128][40];   // +8 pad: 80B row stride, 16B-aligned
    __shared__ short Bs[64][40];
    const int bm = blockIdx.x, bn = blockIdx.y;
    const int tid = threadIdx.x;
    const int wave = tid >> 6, lane = tid & 63;
    const int cl = lane & 15, lg = lane >> 4;

    fx4 acc[2][4];
    #pragma unroll
    for (int m = 0; m < 2; m++)
        #pragma unroll
        for (int n = 0; n < 4; n++) acc[m][n] = (fx4){0.f, 0.f, 0.f, 0.f};

    const int arow = tid >> 1, acol = (tid & 1) * 16;   // A: 128 rows x 32 cols
    const int brow = tid >> 2, bcol = (tid & 3) * 8;    // B: 64 rows x 32 cols

    for (int k0 = 0; k0 < 1024; k0 += 32) {
        if constexpr (MODE == 3) {
            const short* ga = (const short*)Aptr + (size_t)(bm * 128 + arow) * 1024 + k0 + acol;
            bx8 s0 = *(const bx8*)ga;
            bx8 s1 = *(const bx8*)(ga + 8);
            *(bx8*)&As[arow][acol]     = s0;
            *(bx8*)&As[arow][acol + 8] = s1;
        } else {
            const float* ga = (const float*)Aptr + (size_t)(bm * 128 + arow) * 1024 + k0 + acol;
            f4v a0 = *(const f4v*)ga,       a1 = *(const f4v*)(ga + 4);
            f4v a2 = *(const f4v*)(ga + 8), a3 = *(const f4v*)(ga + 12);
            *(bx8*)&As[arow][acol]     = pack8(a0, a1);
            *(bx8*)&As[arow][acol + 8] = pack8(a2, a3);
        }
        {
            const float* gb = W + (size_t)(bn * 64 + brow) * 1024 + k0 + bcol;
            f4v b0 = *(const f4v*)gb, b1 = *(const f4v*)(gb + 4);
            *(bx8*)&Bs[brow][bcol] = pack8(b0, b1);
        }
        __syncthreads();
        bx8 af[2], bf[4];
        #pragma unroll
        for (int m = 0; m < 2; m++) af[m] = *(const bx8*)&As[wave * 32 + m * 16 + cl][lg * 8];
        #pragma unroll
        for (int n = 0; n < 4; n++) bf[n] = *(const bx8*)&Bs[n * 16 + cl][lg * 8];
        #pragma unroll
        for (int m = 0; m < 2; m++)
            #pragma unroll
            for (int n = 0; n < 4; n++)
                acc[m][n] = MFMA_BF16(af[m], bf[n], acc[m][n]);
        __syncthreads();
    }

    // epilogue: C row = bm*128 + wave*32 + m*16 + lg*4 + reg ; col = bn*64 + n*16 + cl
    const int rbase = bm * 128 + wave * 32 + (lg << 2);
    #pragma unroll
    for (int m = 0; m < 2; m++) {
        #pragma unroll
        for (int reg = 0; reg < 4; reg++) {
            const int r = rbase + m * 16 + reg;
            const int b = r >> 11, s = r & 2047;
            #pragma unroll
            for (int n = 0; n < 4; n++) {
                const int d = n * 16 + cl;          // BN=64 => head h = bn, dim = d
                float v = acc[m][n][reg];
                if constexpr (MODE == 0 || MODE == 1) {
                    const float cs = cosT[s * 64 + d], sn = sinT[s * 64 + d];
                    const float partner = acc[m][n ^ 2][reg];   // d ^ 32 lives in frag n^2
                    const float rot = (d < 32) ? -partner : partner;
                    v = v * cs + rot * sn;
                    if constexpr (MODE == 0) v *= 0.125f;       // 1/sqrt(hd) folded into q
                    ((short*)Out)[(size_t)((b * 16 + bn) * 2048 + s) * 64 + d] = f2bf(v);
                } else if constexpr (MODE == 2) {
                    ((short*)Out)[(size_t)((b * 16 + bn) * 2048 + s) * 64 + d] = f2bf(v);
                } else {
                    ((float*)Out)[(size_t)r * 1024 + bn * 64 + d] = v;
                }
            }
        }
    }
}

// ---------------- Attention ----------------
// Swapped QK^T: sacc = mfma(K_frag, Q_frag) = S^T tile, so each lane owns ONE
// q-row (qr = strip + cl) and 16 k-values per tile -> bias via f4v loads, attn
// store direct-from-register f4v, softmax reduce = 2 shuffles (xor 16, 32).
// Register-double-buffered prefetch of K+bias (unroll-by-2); pass A has NO
// barriers/LDS. Pass B: Vt double-buffered in LDS (1 barrier/iter), V
// prefetched to regs at loop top, P wave-local LDS round-trip for PV MFMA.
// Each block does complementary strips (qt, 31-qt) for load balance.
__global__ __launch_bounds__(256, 2) void attn_kernel(
        const short* __restrict__ Q, const short* __restrict__ K,
        const short* __restrict__ V, const float* __restrict__ bias,
        float* __restrict__ attn_out, short* __restrict__ o_buf)
{
    const int S = 2048;
    const int h = blockIdx.y, b = blockIdx.z;
    const int bh = b * 16 + h;
    const int tid = threadIdx.x, wave = tid >> 6, lane = tid & 63;
    const int cl = lane & 15, lg = lane >> 4;
    const size_t base = (size_t)bh * S * 64;

    __shared__ short Vt[2][64][72];    // double-buffered V^T tile [d][k]
    __shared__ short P[4][16][72];     // per-wave P tile [q-local][k]

    const int vkr = tid >> 2, vd0 = (tid & 3) * 16;   // V staging indices

#define LOADKB(KARR, BARR, t)                                                    \
    { _Pragma("unroll") for (int n = 0; n < 4; ++n) {                            \
        const short* kp = K + base + (size_t)((t) * 64 + n * 16 + cl) * 64 + lg * 8; \
        KARR[n][0] = *(const bx8*)kp; KARR[n][1] = *(const bx8*)(kp + 32); }     \
      _Pragma("unroll") for (int n = 0; n < 4; ++n)                              \
        BARR[n] = *(const f4v*)(brow + (t) * 64 + n * 16 + (lg << 2)); }

#define COMP_A(KARR, BARR, t)                                                    \
    { fx4 sacc[4];                                                               \
      _Pragma("unroll") for (int n = 0; n < 4; ++n) {                            \
        sacc[n] = (fx4){0.f, 0.f, 0.f, 0.f};                                     \
        sacc[n] = MFMA_BF16(KARR[n][0], qf0, sacc[n]);                           \
        sacc[n] = MFMA_BF16(KARR[n][1], qf1, sacc[n]); }                         \
      float sv[4][4]; float tmax = -3.0e38f;                                     \
      _Pragma("unroll") for (int n = 0; n < 4; ++n)                              \
        _Pragma("unroll") for (int r = 0; r < 4; ++r) {                          \
          const int kc = (t) * 64 + n * 16 + (lg << 2) + r;                      \
          sv[n][r] = (kc <= qr) ? (sacc[n][r] + BARR[n][r]) : -3.0e38f;          \
          tmax = fmaxf(tmax, sv[n][r]); }                                        \
      tmax = fmaxf(tmax, __shfl_xor(tmax, 16));                                  \
      tmax = fmaxf(tmax, __shfl_xor(tmax, 32));                                  \
      const float mnew = fmaxf(m, tmax);                                         \
      float sum = 0.f;                                                           \
      _Pragma("unroll") for (int n = 0; n < 4; ++n)                              \
        _Pragma("unroll") for (int r = 0; r < 4; ++r)                            \
          sum += __expf(sv[n][r] - mnew);                                        \
      sum += __shfl_xor(sum, 16);                                                \
      sum += __shfl_xor(sum, 32);                                                \
      l = l * __expf(m - mnew) + sum;                                            \
      m = mnew; }

#define LOADV(t)                                                                 \
    { const short* vp = V + base + (size_t)((t) * 64 + vkr) * 64 + vd0;          \
      vr0 = *(const bx8*)vp; vr1 = *(const bx8*)(vp + 8); }

#define VSTORE(t)                                                                \
    { _Pragma("unroll") for (int j = 0; j < 8; ++j) Vt[(t) & 1][vd0 + j][vkr] = vr0[j]; \
      _Pragma("unroll") for (int j = 0; j < 8; ++j) Vt[(t) & 1][vd0 + 8 + j][vkr] = vr1[j]; }

#define COMP_B(KARR, BARR, t)                                                    \
    { fx4 sacc[4];                                                               \
      _Pragma("unroll") for (int n = 0; n < 4; ++n) {                            \
        sacc[n] = (fx4){0.f, 0.f, 0.f, 0.f};                                     \
        sacc[n] = MFMA_BF16(KARR[n][0], qf0, sacc[n]);                           \
        sacc[n] = MFMA_BF16(KARR[n][1], qf1, sacc[n]); }                         \
      float p[4][4];                                                             \
      _Pragma("unroll") for (int n = 0; n < 4; ++n)                              \
        _Pragma("unroll") for (int r = 0; r < 4; ++r) {                          \
          const int kc = (t) * 64 + n * 16 + (lg << 2) + r;                      \
          const float sv = (kc <= qr) ? (sacc[n][r] + BARR[n][r]) : -3.0e38f;    \
          p[n][r] = __expf(sv - m) * invl; }                                     \
      _Pragma("unroll") for (int n = 0; n < 4; ++n) {                            \
        f4v st = (f4v){p[n][0], p[n][1], p[n][2], p[n][3]};                      \
        *(f4v*)(attn_out + arow_base + (t) * 64 + n * 16 + (lg << 2)) = st;      \
        sx4 pb;                                                                  \
        pb[0] = f2bf(p[n][0]); pb[1] = f2bf(p[n][1]);                            \
        pb[2] = f2bf(p[n][2]); pb[3] = f2bf(p[n][3]);                            \
        *(sx4*)&P[wave][cl][n * 16 + (lg << 2)] = pb; }                          \
      _Pragma("unroll") for (int kk = 0; kk < 2; ++kk) {                         \
        bx8 pa = *(const bx8*)&P[wave][cl][kk * 32 + lg * 8];                    \
        _Pragma("unroll") for (int n = 0; n < 4; ++n) {                          \
          bx8 vb = *(const bx8*)&Vt[(t) & 1][n * 16 + cl][kk * 32 + lg * 8];     \
          oacc[n] = MFMA_BF16(pa, vb, oacc[n]); } } }

    for (int sidx = 0; sidx < 2; ++sidx) {
        const int qt = sidx ? (31 - blockIdx.x) : blockIdx.x;

        bx8 qf0, qf1;
        {
            const short* qp = Q + base + (size_t)(qt * 64 + wave * 16 + cl) * 64 + lg * 8;
            qf0 = *(const bx8*)qp;
            qf1 = *(const bx8*)(qp + 32);
        }
        const int qr  = qt * 64 + wave * 16 + cl;        // lane's q row
        const int sq0 = qt * 64 + wave * 16 + (lg << 2); // lane's first O row
        const float* brow = bias + (size_t)qr * 2048;
        const size_t arow_base = ((size_t)bh * S + qr) * S;

        float m = -3.0e38f, l = 0.f;
        bx8 kA[4][2], kB[4][2];
        f4v bA[4], bB[4];

        // ---- PASS A: online row max/sum (no barriers, no LDS) ----
        LOADKB(kA, bA, 0);
        int kt = 0;
        for (; kt + 1 <= qt; kt += 2) {
            LOADKB(kB, bB, kt + 1);
            COMP_A(kA, bA, kt);
            if (kt + 2 <= qt) LOADKB(kA, bA, kt + 2);
            COMP_A(kB, bB, kt + 1);
        }
        if (kt <= qt) COMP_A(kA, bA, kt);
        const float invl = 1.0f / l;

        fx4 oacc[4];
        #pragma unroll
        for (int n = 0; n < 4; n++) oacc[n] = (fx4){0.f, 0.f, 0.f, 0.f};

        // ---- PASS B ----
        bx8 vr0, vr1;
        LOADV(0);
        LOADKB(kA, bA, 0);
        __syncthreads();               // prev strip's Vt readers done
        VSTORE(0);
        __syncthreads();
        kt = 0;
        for (; kt + 1 <= qt; kt += 2) {
            LOADV(kt + 1);
            LOADKB(kB, bB, kt + 1);
            COMP_B(kA, bA, kt);
            VSTORE(kt + 1);
            __syncthreads();
            if (kt + 2 <= qt) { LOADV(kt + 2); LOADKB(kA, bA, kt + 2); }
            COMP_B(kB, bB, kt + 1);
            if (kt + 2 <= qt) { VSTORE(kt + 2); __syncthreads(); }
        }
        if (kt <= qt) COMP_B(kA, bA, kt);

        // write O tile to o_buf[b][s][h*64+d] (bf16); C row = lg*4+reg, col = cl
        #pragma unroll
        for (int reg = 0; reg < 4; reg++) {
            const int sq = sq0 + reg;
            #pragma unroll
            for (int n = 0; n < 4; n++) {
                const int d = n * 16 + cl;
                o_buf[(size_t)(b * 2048 + sq) * 1024 + h * 64 + d] = f2bf(oacc[n][reg]);
            }
        }

        // zero-fill strict upper triangle tiles (k >= (qt+1)*64) for these 64 q rows
        const int c0 = (qt + 1) * 64;
        if (c0 < S) {
            const int count = S - c0;          // multiple of 64
            const int total = 64 * count;
            const f4v z = (f4v){0.f, 0.f, 0.f, 0.f};
            for (int i = tid * 4; i < total; i += 1024) {
                const int row = i / count;
                const int cc = c0 + (i % count);
                *(f4v*)(attn_out + ((size_t)bh * S + qt * 64 + row) * S + cc) = z;
            }
        }
    }
#undef LOADKB
#undef COMP_A
#undef LOADV
#undef VSTORE
#undef COMP_B
}

extern "C" void kernel_launch(void* const* d_in, const int* in_sizes, int n_in,
                              void* d_out, int out_size, void* d_ws, size_t ws_size,
                              hipStream_t stream) {
    const float* x    = (const float*)d_in[0];
    const float* Wq   = (const float*)d_in[1];
    const float* Wk   = (const float*)d_in[2];
    const float* Wv   = (const float*)d_in[3];
    const float* Wo   = (const float*)d_in[4];
    const float* bias = (const float*)d_in[5];

    float* out  = (float*)d_out;                       // [2,2048,1024] f32
    float* attn = out + (size_t)2 * 2048 * 1024;       // [2,16,2048,2048] f32

    char* ws = (char*)d_ws;
    float* cosT = (float*)ws;                          // 2048*64 f32
    float* sinT = cosT + 2048 * 64;
    short* q_rope = (short*)(ws + (size_t)2 * 2048 * 64 * 4);   // 1 MiB offset
    short* k_rope = q_rope + (size_t)32 * 2048 * 64;
    short* v_bf   = k_rope + (size_t)32 * 2048 * 64;
    short* o_buf  = v_bf   + (size_t)32 * 2048 * 64;

    rope_table_kernel<<<512, 256, 0, stream>>>(cosT, sinT);
    dim3 g(32, 16);
    gemm_kernel<0><<<g, 256, 0, stream>>>(x, Wq, cosT, sinT, q_rope);
    gemm_kernel<1><<<g, 256, 0, stream>>>(x, Wk, cosT, sinT, k_rope);
    gemm_kernel<2><<<g, 256, 0, stream>>>(x, Wv, cosT, sinT, v_bf);
    attn_kernel<<<dim3(16, 16, 2), 256, 0, stream>>>(q_rope, k_rope, v_bf, bias, attn, o_buf);
    gemm_kernel<3><<<g, 256, 0, stream>>>(o_buf, Wo, cosT, sinT, out);
}

// Round 5
// 346.228 us; speedup vs baseline: 2.0920x; 1.1794x over previous
//
#include <hip/hip_runtime.h>
#include <hip/hip_bf16.h>
#include <math.h>

// Shapes: B=2, S=2048, H=1024, nh=16, hd=64. Inputs f32, outputs f32.
// d_out = [out: 2*2048*1024] ++ [attn: 2*16*2048*2048], both f32.
// Internals bf16: x_bf, W*_bf, q_rope/k_rope/v_bf/o_buf.

typedef __attribute__((ext_vector_type(8))) short bx8;   // 8 bf16 (4 VGPRs)
typedef __attribute__((ext_vector_type(4))) short sx4;   // 4 bf16
typedef __attribute__((ext_vector_type(4))) float fx4;   // MFMA accum
typedef __attribute__((ext_vector_type(4))) float f4v;

#define MFMA_BF16(a, b, c) __builtin_amdgcn_mfma_f32_16x16x32_bf16(a, b, c, 0, 0, 0)

__device__ __forceinline__ short f2bf(float f) {
    union { float f; unsigned u; } v; v.f = f;
    unsigned u = v.u;
    u += 0x7fffu + ((u >> 16) & 1u);   // RTNE
    return (short)(u >> 16);
}

__device__ __forceinline__ bx8 pack8(f4v a, f4v b) {
    bx8 r;
    r[0] = f2bf(a[0]); r[1] = f2bf(a[1]); r[2] = f2bf(a[2]); r[3] = f2bf(a[3]);
    r[4] = f2bf(b[0]); r[5] = f2bf(b[1]); r[6] = f2bf(b[2]); r[7] = f2bf(b[3]);
    return r;
}

__device__ __forceinline__ void gload_lds16(const short* g, short* l) {
    __builtin_amdgcn_global_load_lds(
        (const __attribute__((address_space(1))) void*)g,
        (__attribute__((address_space(3))) void*)l, 16, 0, 0);
}

// ---------------- bf16 cast: dst = [x:4M][Wq:1M][Wk:1M][Wv:1M][Wo:1M] elems
__global__ __launch_bounds__(256) void cast_kernel(
        const float* __restrict__ x, const float* __restrict__ Wq,
        const float* __restrict__ Wk, const float* __restrict__ Wv,
        const float* __restrict__ Wo, short* __restrict__ dst)
{
    const size_t e0 = ((size_t)blockIdx.x * 256 + threadIdx.x) * 8;
    const float* src; size_t off;
    if (e0 < (4u << 20)) { src = x; off = e0; }
    else {
        const int j = (int)((e0 - (4u << 20)) >> 20);
        src = (j == 0) ? Wq : (j == 1) ? Wk : (j == 2) ? Wv : Wo;
        off = (e0 - (4u << 20)) & ((1u << 20) - 1);
    }
    f4v a = *(const f4v*)(src + off);
    f4v b = *(const f4v*)(src + off + 4);
    *(bx8*)(dst + e0) = pack8(a, b);
}

// ---------------- RoPE cos/sin table: [2048][64] f32 each ----------------
__global__ void rope_table_kernel(float* __restrict__ cosT, float* __restrict__ sinT) {
    int i = blockIdx.x * 256 + threadIdx.x;
    if (i >= 2048 * 64) return;
    int s = i >> 6, d = i & 63;
    int fi = d & 31;                               // emb = concat(freqs, freqs)
    float inv_freq = powf(10000.0f, -(float)fi / 32.0f);
    float ang = (float)s * inv_freq;
    cosT[i] = cosf(ang);
    sinT[i] = sinf(ang);
}

// ---------------- GEMM 128x128, BK=64, global_load_lds + XOR chunk swizzle.
// C[4096][1024] = A[4096][1024](bf16) @ W[1024][1024]^T(bf16).
// 256 thr = 4 waves (2x2), each wave 64x64 = 4x4 frags of 16x16x32.
// LDS linear (gload_lds dest), global source chunk pre-swizzled c^=(row&7),
// ds_read applies the same XOR -> conflict-free b128 reads (rule 21c).
// OUTPROJ=0: z selects {Wq,Wk,Wv}; RoPE(+0.125 for z==0) epilogue, bf16 out
//            to q_rope base + z*8MB, layout [bh][s][d].
// OUTPROJ=1: plain epilogue, f32 out row-major [4096][1024].
template<int OUTPROJ>
__global__ __launch_bounds__(256) void gemm128(
        const short* __restrict__ A, const short* __restrict__ W0,
        const short* __restrict__ W1, const short* __restrict__ W2,
        const float* __restrict__ cosT, const float* __restrict__ sinT,
        void* __restrict__ Out)
{
    __shared__ short As[128][64];
    __shared__ short Bs[128][64];
    const int bm = blockIdx.x, bn = blockIdx.y, z = blockIdx.z;
    const short* W = OUTPROJ ? W0 : (z == 0 ? W0 : (z == 1 ? W1 : W2));
    const int tid = threadIdx.x, w = tid >> 6, lane = tid & 63;
    const int cl = lane & 15, lg = lane >> 4;
    const int srow = lane >> 3;                 // 0..7 within staged 8-row block
    const int schunk = (lane & 7) ^ srow;       // swizzled global 16B-chunk

    fx4 acc[4][4];
    #pragma unroll
    for (int mi = 0; mi < 4; ++mi)
        #pragma unroll
        for (int ni = 0; ni < 4; ++ni) acc[mi][ni] = (fx4){0.f, 0.f, 0.f, 0.f};

    const int wr = (w >> 1) * 64, wc = (w & 1) * 64;

    for (int k0 = 0; k0 < 1024; k0 += 64) {
        __syncthreads();                        // prev compute done
        #pragma unroll
        for (int i = 0; i < 4; ++i) {
            const int rbase = w * 32 + i * 8;
            gload_lds16(A + (size_t)(bm * 128 + rbase + srow) * 1024 + k0 + schunk * 8,
                        &As[rbase][0]);
            gload_lds16(W + (size_t)(bn * 128 + rbase + srow) * 1024 + k0 + schunk * 8,
                        &Bs[rbase][0]);
        }
        __syncthreads();                        // staging visible
        #pragma unroll
        for (int kk = 0; kk < 2; ++kk) {
            bx8 af[4], bf[4];
            #pragma unroll
            for (int i = 0; i < 4; ++i) {
                const int ra = wr + i * 16 + cl;
                af[i] = *(const bx8*)&As[ra][((kk * 4 + lg) ^ (ra & 7)) * 8];
                const int rb = wc + i * 16 + cl;
                bf[i] = *(const bx8*)&Bs[rb][((kk * 4 + lg) ^ (rb & 7)) * 8];
            }
            #pragma unroll
            for (int mi = 0; mi < 4; ++mi)
                #pragma unroll
                for (int ni = 0; ni < 4; ++ni)
                    acc[mi][ni] = MFMA_BF16(af[mi], bf[ni], acc[mi][ni]);
        }
    }

    // epilogue: row = bm*128 + wr + mi*16 + lg*4 + reg ; col = bn*128 + wc + ni*16 + cl
    #pragma unroll
    for (int mi = 0; mi < 4; ++mi) {
        #pragma unroll
        for (int reg = 0; reg < 4; ++reg) {
            const int r = bm * 128 + wr + mi * 16 + (lg << 2) + reg;
            if constexpr (OUTPROJ) {
                #pragma unroll
                for (int ni = 0; ni < 4; ++ni) {
                    const int col = bn * 128 + wc + ni * 16 + cl;
                    ((float*)Out)[(size_t)r * 1024 + col] = acc[mi][ni][reg];
                }
            } else {
                const int b = r >> 11, s = r & 2047;
                const int h = bn * 2 + (wc >> 6);
                short* dst = (short*)Out + (size_t)z * 32 * 2048 * 64
                           + (size_t)((b * 16 + h) * 2048 + s) * 64;
                #pragma unroll
                for (int ni = 0; ni < 4; ++ni) {
                    const int d = ni * 16 + cl;
                    float v = acc[mi][ni][reg];
                    if (z <= 1) {
                        const float cs = cosT[s * 64 + d], sn = sinT[s * 64 + d];
                        const float partner = acc[mi][ni ^ 2][reg];   // d ^ 32
                        const float rot = (d < 32) ? -partner : partner;
                        v = v * cs + rot * sn;
                        if (z == 0) v *= 0.125f;    // 1/sqrt(hd) folded into q
                    }
                    dst[d] = f2bf(v);
                }
            }
        }
    }
}

// ---------------- Attention (unchanged from R3) ----------------
__global__ __launch_bounds__(256, 2) void attn_kernel(
        const short* __restrict__ Q, const short* __restrict__ K,
        const short* __restrict__ V, const float* __restrict__ bias,
        float* __restrict__ attn_out, short* __restrict__ o_buf)
{
    const int S = 2048;
    const int h = blockIdx.y, b = blockIdx.z;
    const int bh = b * 16 + h;
    const int tid = threadIdx.x, wave = tid >> 6, lane = tid & 63;
    const int cl = lane & 15, lg = lane >> 4;
    const size_t base = (size_t)bh * S * 64;

    __shared__ short Vt[2][64][72];    // double-buffered V^T tile [d][k]
    __shared__ short P[4][16][72];     // per-wave P tile [q-local][k]

    const int vkr = tid >> 2, vd0 = (tid & 3) * 16;   // V staging indices

#define LOADKB(KARR, BARR, t)                                                    \
    { _Pragma("unroll") for (int n = 0; n < 4; ++n) {                            \
        const short* kp = K + base + (size_t)((t) * 64 + n * 16 + cl) * 64 + lg * 8; \
        KARR[n][0] = *(const bx8*)kp; KARR[n][1] = *(const bx8*)(kp + 32); }     \
      _Pragma("unroll") for (int n = 0; n < 4; ++n)                              \
        BARR[n] = *(const f4v*)(brow + (t) * 64 + n * 16 + (lg << 2)); }

#define COMP_A(KARR, BARR, t)                                                    \
    { fx4 sacc[4];                                                               \
      _Pragma("unroll") for (int n = 0; n < 4; ++n) {                            \
        sacc[n] = (fx4){0.f, 0.f, 0.f, 0.f};                                     \
        sacc[n] = MFMA_BF16(KARR[n][0], qf0, sacc[n]);                           \
        sacc[n] = MFMA_BF16(KARR[n][1], qf1, sacc[n]); }                         \
      float sv[4][4]; float tmax = -3.0e38f;                                     \
      _Pragma("unroll") for (int n = 0; n < 4; ++n)                              \
        _Pragma("unroll") for (int r = 0; r < 4; ++r) {                          \
          const int kc = (t) * 64 + n * 16 + (lg << 2) + r;                      \
          sv[n][r] = (kc <= qr) ? (sacc[n][r] + BARR[n][r]) : -3.0e38f;          \
          tmax = fmaxf(tmax, sv[n][r]); }                                        \
      tmax = fmaxf(tmax, __shfl_xor(tmax, 16));                                  \
      tmax = fmaxf(tmax, __shfl_xor(tmax, 32));                                  \
      const float mnew = fmaxf(m, tmax);                                         \
      float sum = 0.f;                                                           \
      _Pragma("unroll") for (int n = 0; n < 4; ++n)                              \
        _Pragma("unroll") for (int r = 0; r < 4; ++r)                            \
          sum += __expf(sv[n][r] - mnew);                                        \
      sum += __shfl_xor(sum, 16);                                                \
      sum += __shfl_xor(sum, 32);                                                \
      l = l * __expf(m - mnew) + sum;                                            \
      m = mnew; }

#define LOADV(t)                                                                 \
    { const short* vp = V + base + (size_t)((t) * 64 + vkr) * 64 + vd0;          \
      vr0 = *(const bx8*)vp; vr1 = *(const bx8*)(vp + 8); }

#define VSTORE(t)                                                                \
    { _Pragma("unroll") for (int j = 0; j < 8; ++j) Vt[(t) & 1][vd0 + j][vkr] = vr0[j]; \
      _Pragma("unroll") for (int j = 0; j < 8; ++j) Vt[(t) & 1][vd0 + 8 + j][vkr] = vr1[j]; }

#define COMP_B(KARR, BARR, t)                                                    \
    { fx4 sacc[4];                                                               \
      _Pragma("unroll") for (int n = 0; n < 4; ++n) {                            \
        sacc[n] = (fx4){0.f, 0.f, 0.f, 0.f};                                     \
        sacc[n] = MFMA_BF16(KARR[n][0], qf0, sacc[n]);                           \
        sacc[n] = MFMA_BF16(KARR[n][1], qf1, sacc[n]); }                         \
      float p[4][4];                                                             \
      _Pragma("unroll") for (int n = 0; n < 4; ++n)                              \
        _Pragma("unroll") for (int r = 0; r < 4; ++r) {                          \
          const int kc = (t) * 64 + n * 16 + (lg << 2) + r;                      \
          const float sv = (kc <= qr) ? (sacc[n][r] + BARR[n][r]) : -3.0e38f;    \
          p[n][r] = __expf(sv - m) * invl; }                                     \
      _Pragma("unroll") for (int n = 0; n < 4; ++n) {                            \
        f4v st = (f4v){p[n][0], p[n][1], p[n][2], p[n][3]};                      \
        *(f4v*)(attn_out + arow_base + (t) * 64 + n * 16 + (lg << 2)) = st;      \
        sx4 pb;                                                                  \
        pb[0] = f2bf(p[n][0]); pb[1] = f2bf(p[n][1]);                            \
        pb[2] = f2bf(p[n][2]); pb[3] = f2bf(p[n][3]);                            \
        *(sx4*)&P[wave][cl][n * 16 + (lg << 2)] = pb; }                          \
      _Pragma("unroll") for (int kk = 0; kk < 2; ++kk) {                         \
        bx8 pa = *(const bx8*)&P[wave][cl][kk * 32 + lg * 8];                    \
        _Pragma("unroll") for (int n = 0; n < 4; ++n) {                          \
          bx8 vb = *(const bx8*)&Vt[(t) & 1][n * 16 + cl][kk * 32 + lg * 8];     \
          oacc[n] = MFMA_BF16(pa, vb, oacc[n]); } } }

    for (int sidx = 0; sidx < 2; ++sidx) {
        const int qt = sidx ? (31 - blockIdx.x) : blockIdx.x;

        bx8 qf0, qf1;
        {
            const short* qp = Q + base + (size_t)(qt * 64 + wave * 16 + cl) * 64 + lg * 8;
            qf0 = *(const bx8*)qp;
            qf1 = *(const bx8*)(qp + 32);
        }
        const int qr  = qt * 64 + wave * 16 + cl;        // lane's q row
        const int sq0 = qt * 64 + wave * 16 + (lg << 2); // lane's first O row
        const float* brow = bias + (size_t)qr * 2048;
        const size_t arow_base = ((size_t)bh * S + qr) * S;

        float m = -3.0e38f, l = 0.f;
        bx8 kA[4][2], kB[4][2];
        f4v bA[4], bB[4];

        // ---- PASS A: online row max/sum (no barriers, no LDS) ----
        LOADKB(kA, bA, 0);
        int kt = 0;
        for (; kt + 1 <= qt; kt += 2) {
            LOADKB(kB, bB, kt + 1);
            COMP_A(kA, bA, kt);
            if (kt + 2 <= qt) LOADKB(kA, bA, kt + 2);
            COMP_A(kB, bB, kt + 1);
        }
        if (kt <= qt) COMP_A(kA, bA, kt);
        const float invl = 1.0f / l;

        fx4 oacc[4];
        #pragma unroll
        for (int n = 0; n < 4; n++) oacc[n] = (fx4){0.f, 0.f, 0.f, 0.f};

        // ---- PASS B ----
        bx8 vr0, vr1;
        LOADV(0);
        LOADKB(kA, bA, 0);
        __syncthreads();               // prev strip's Vt readers done
        VSTORE(0);
        __syncthreads();
        kt = 0;
        for (; kt + 1 <= qt; kt += 2) {
            LOADV(kt + 1);
            LOADKB(kB, bB, kt + 1);
            COMP_B(kA, bA, kt);
            VSTORE(kt + 1);
            __syncthreads();
            if (kt + 2 <= qt) { LOADV(kt + 2); LOADKB(kA, bA, kt + 2); }
            COMP_B(kB, bB, kt + 1);
            if (kt + 2 <= qt) { VSTORE(kt + 2); __syncthreads(); }
        }
        if (kt <= qt) COMP_B(kA, bA, kt);

        // write O tile to o_buf[b][s][h*64+d] (bf16); C row = lg*4+reg, col = cl
        #pragma unroll
        for (int reg = 0; reg < 4; reg++) {
            const int sq = sq0 + reg;
            #pragma unroll
            for (int n = 0; n < 4; n++) {
                const int d = n * 16 + cl;
                o_buf[(size_t)(b * 2048 + sq) * 1024 + h * 64 + d] = f2bf(oacc[n][reg]);
            }
        }

        // zero-fill strict upper triangle tiles (k >= (qt+1)*64) for these 64 q rows
        const int c0 = (qt + 1) * 64;
        if (c0 < S) {
            const int count = S - c0;          // multiple of 64
            const int total = 64 * count;
            const f4v z = (f4v){0.f, 0.f, 0.f, 0.f};
            for (int i = tid * 4; i < total; i += 1024) {
                const int row = i / count;
                const int cc = c0 + (i % count);
                *(f4v*)(attn_out + ((size_t)bh * S + qt * 64 + row) * S + cc) = z;
            }
        }
    }
#undef LOADKB
#undef COMP_A
#undef LOADV
#undef VSTORE
#undef COMP_B
}

extern "C" void kernel_launch(void* const* d_in, const int* in_sizes, int n_in,
                              void* d_out, int out_size, void* d_ws, size_t ws_size,
                              hipStream_t stream) {
    const float* x    = (const float*)d_in[0];
    const float* Wq   = (const float*)d_in[1];
    const float* Wk   = (const float*)d_in[2];
    const float* Wv   = (const float*)d_in[3];
    const float* Wo   = (const float*)d_in[4];
    const float* bias = (const float*)d_in[5];

    float* out  = (float*)d_out;                       // [2,2048,1024] f32
    float* attn = out + (size_t)2 * 2048 * 1024;       // [2,16,2048,2048] f32

    char* ws = (char*)d_ws;
    short* x_bf  = (short*)ws;                         // 4M shorts
    short* wq_bf = x_bf + (size_t)4 * 1024 * 1024;
    short* wk_bf = wq_bf + (size_t)1024 * 1024;
    short* wv_bf = wk_bf + (size_t)1024 * 1024;
    short* wo_bf = wv_bf + (size_t)1024 * 1024;        // cast dst ends at 16MB
    float* cosT  = (float*)(ws + (size_t)16 * 1024 * 1024);
    float* sinT  = cosT + 2048 * 64;
    short* q_rope = (short*)(ws + (size_t)18 * 1024 * 1024);
    short* k_rope = q_rope + (size_t)32 * 2048 * 64;
    short* v_bf   = k_rope + (size_t)32 * 2048 * 64;
    short* o_buf  = v_bf   + (size_t)32 * 2048 * 64;   // ends at 50MB

    cast_kernel<<<4096, 256, 0, stream>>>(x, Wq, Wk, Wv, Wo, x_bf);
    rope_table_kernel<<<512, 256, 0, stream>>>(cosT, sinT);
    gemm128<0><<<dim3(32, 8, 3), 256, 0, stream>>>(x_bf, wq_bf, wk_bf, wv_bf,
                                                   cosT, sinT, q_rope);
    attn_kernel<<<dim3(16, 16, 2), 256, 0, stream>>>(q_rope, k_rope, v_bf, bias, attn, o_buf);
    gemm128<1><<<dim3(32, 8, 1), 256, 0, stream>>>(o_buf, wo_bf, wo_bf, wo_bf,
                                                   cosT, sinT, out);
}

// Round 6
// 319.642 us; speedup vs baseline: 2.2660x; 1.0832x over previous
//
#include <hip/hip_runtime.h>
#include <hip/hip_bf16.h>
#include <math.h>

// Shapes: B=2, S=2048, H=1024, nh=16, hd=64. Inputs f32, outputs f32.
// d_out = [out: 2*2048*1024] ++ [attn: 2*16*2048*2048], both f32.
// Internals bf16: x_bf/W*_bf/bias_bf, q_rope/k_rope/v_bf/o_buf(=x_bf).

typedef __attribute__((ext_vector_type(8))) short bx8;   // 8 bf16 (4 VGPRs)
typedef __attribute__((ext_vector_type(4))) short sx4;   // 4 bf16
typedef __attribute__((ext_vector_type(4))) float fx4;   // MFMA accum
typedef __attribute__((ext_vector_type(4))) float f4v;

#define MFMA_BF16(a, b, c) __builtin_amdgcn_mfma_f32_16x16x32_bf16(a, b, c, 0, 0, 0)

__device__ __forceinline__ short f2bf(float f) {
    union { float f; unsigned u; } v; v.f = f;
    unsigned u = v.u;
    u += 0x7fffu + ((u >> 16) & 1u);   // RTNE
    return (short)(u >> 16);
}
__device__ __forceinline__ float bf2f(short s) {
    union { unsigned u; float f; } v; v.u = ((unsigned)(unsigned short)s) << 16;
    return v.f;
}

__device__ __forceinline__ bx8 pack8(f4v a, f4v b) {
    bx8 r;
    r[0] = f2bf(a[0]); r[1] = f2bf(a[1]); r[2] = f2bf(a[2]); r[3] = f2bf(a[3]);
    r[4] = f2bf(b[0]); r[5] = f2bf(b[1]); r[6] = f2bf(b[2]); r[7] = f2bf(b[3]);
    return r;
}

__device__ __forceinline__ void gload_lds16(const short* g, short* l) {
    __builtin_amdgcn_global_load_lds(
        (const __attribute__((address_space(1))) void*)g,
        (__attribute__((address_space(3))) void*)l, 16, 0, 0);
}

// ---------------- bf16 cast: dst = [x:4M][Wq:1M][Wk:1M][Wv:1M][Wo:1M][bias:4M]
__global__ __launch_bounds__(256) void cast_kernel(
        const float* __restrict__ x, const float* __restrict__ Wq,
        const float* __restrict__ Wk, const float* __restrict__ Wv,
        const float* __restrict__ Wo, const float* __restrict__ bias,
        short* __restrict__ dst)
{
    const size_t M1 = 1u << 20;
    const size_t e0 = ((size_t)blockIdx.x * 256 + threadIdx.x) * 8;
    const float* src; size_t off;
    if (e0 < 4 * M1) { src = x; off = e0; }
    else if (e0 < 8 * M1) {
        const int j = (int)((e0 - 4 * M1) >> 20);
        src = (j == 0) ? Wq : (j == 1) ? Wk : (j == 2) ? Wv : Wo;
        off = (e0 - 4 * M1) & (M1 - 1);
    } else { src = bias; off = e0 - 8 * M1; }
    f4v a = *(const f4v*)(src + off);
    f4v b = *(const f4v*)(src + off + 4);
    *(bx8*)(dst + e0) = pack8(a, b);
}

// ---------------- RoPE cos/sin table: [2048][64] f32 each ----------------
__global__ void rope_table_kernel(float* __restrict__ cosT, float* __restrict__ sinT) {
    int i = blockIdx.x * 256 + threadIdx.x;
    if (i >= 2048 * 64) return;
    int s = i >> 6, d = i & 63;
    int fi = d & 31;                               // emb = concat(freqs, freqs)
    float inv_freq = powf(10000.0f, -(float)fi / 32.0f);
    float ang = (float)s * inv_freq;
    cosT[i] = cosf(ang);
    sinT[i] = sinf(ang);
}

// ---------------- GEMM 128x128, BK=64, global_load_lds + XOR chunk swizzle.
template<int OUTPROJ>
__global__ __launch_bounds__(256) void gemm128(
        const short* __restrict__ A, const short* __restrict__ W0,
        const short* __restrict__ W1, const short* __restrict__ W2,
        const float* __restrict__ cosT, const float* __restrict__ sinT,
        void* __restrict__ Out)
{
    __shared__ short As[128][64];
    __shared__ short Bs[128][64];
    const int bm = blockIdx.x, bn = blockIdx.y, z = blockIdx.z;
    const short* W = OUTPROJ ? W0 : (z == 0 ? W0 : (z == 1 ? W1 : W2));
    const int tid = threadIdx.x, w = tid >> 6, lane = tid & 63;
    const int cl = lane & 15, lg = lane >> 4;
    const int srow = lane >> 3;                 // 0..7 within staged 8-row block
    const int schunk = (lane & 7) ^ srow;       // swizzled global 16B-chunk

    fx4 acc[4][4];
    #pragma unroll
    for (int mi = 0; mi < 4; ++mi)
        #pragma unroll
        for (int ni = 0; ni < 4; ++ni) acc[mi][ni] = (fx4){0.f, 0.f, 0.f, 0.f};

    const int wr = (w >> 1) * 64, wc = (w & 1) * 64;

    for (int k0 = 0; k0 < 1024; k0 += 64) {
        __syncthreads();                        // prev compute done
        #pragma unroll
        for (int i = 0; i < 4; ++i) {
            const int rbase = w * 32 + i * 8;
            gload_lds16(A + (size_t)(bm * 128 + rbase + srow) * 1024 + k0 + schunk * 8,
                        &As[rbase][0]);
            gload_lds16(W + (size_t)(bn * 128 + rbase + srow) * 1024 + k0 + schunk * 8,
                        &Bs[rbase][0]);
        }
        __syncthreads();                        // staging visible
        #pragma unroll
        for (int kk = 0; kk < 2; ++kk) {
            bx8 af[4], bf[4];
            #pragma unroll
            for (int i = 0; i < 4; ++i) {
                const int ra = wr + i * 16 + cl;
                af[i] = *(const bx8*)&As[ra][((kk * 4 + lg) ^ (ra & 7)) * 8];
                const int rb = wc + i * 16 + cl;
                bf[i] = *(const bx8*)&Bs[rb][((kk * 4 + lg) ^ (rb & 7)) * 8];
            }
            #pragma unroll
            for (int mi = 0; mi < 4; ++mi)
                #pragma unroll
                for (int ni = 0; ni < 4; ++ni)
                    acc[mi][ni] = MFMA_BF16(af[mi], bf[ni], acc[mi][ni]);
        }
    }

    #pragma unroll
    for (int mi = 0; mi < 4; ++mi) {
        #pragma unroll
        for (int reg = 0; reg < 4; ++reg) {
            const int r = bm * 128 + wr + mi * 16 + (lg << 2) + reg;
            if constexpr (OUTPROJ) {
                #pragma unroll
                for (int ni = 0; ni < 4; ++ni) {
                    const int col = bn * 128 + wc + ni * 16 + cl;
                    ((float*)Out)[(size_t)r * 1024 + col] = acc[mi][ni][reg];
                }
            } else {
                const int b = r >> 11, s = r & 2047;
                const int h = bn * 2 + (wc >> 6);
                short* dst = (short*)Out + (size_t)z * 32 * 2048 * 64
                           + (size_t)((b * 16 + h) * 2048 + s) * 64;
                #pragma unroll
                for (int ni = 0; ni < 4; ++ni) {
                    const int d = ni * 16 + cl;
                    float v = acc[mi][ni][reg];
                    if (z <= 1) {
                        const float cs = cosT[s * 64 + d], sn = sinT[s * 64 + d];
                        const float partner = acc[mi][ni ^ 2][reg];   // d ^ 32
                        const float rot = (d < 32) ? -partner : partner;
                        v = v * cs + rot * sn;
                        if (z == 0) v *= 0.125f;    // 1/sqrt(hd) folded into q
                    }
                    dst[d] = f2bf(v);
                }
            }
        }
    }
}

// ---------------- Attention: QBLK=128 (8 waves x 16 q-rows), 256 blocks.
// K staged ONCE per block into LDS (gload_lds + XOR swizzle, dbuf); bias bf16
// register-prefetched; V reg->LDS transposed (dbuf); swapped QK^T (lane owns
// one q-row). XCD-local decode: same (b,h) -> same XCD for K/V/Q L2 residency.
// Strip pair (qt, 15-qt): NT = 2qt+2 tiles (always even -> clean 2-unroll).
__global__ __launch_bounds__(512, 2) void attn_kernel(
        const short* __restrict__ Q, const short* __restrict__ K,
        const short* __restrict__ V, const short* __restrict__ bias_bf,
        float* __restrict__ attn_out, short* __restrict__ o_buf)
{
    const int S = 2048;
    const int dd = blockIdx.x;                 // 0..255
    const int xcd = dd & 7, slot = dd >> 3;    // dispatch d -> XCD d%8
    const int bh = xcd * 4 + (slot >> 3);      // 4 (b,h) pairs per XCD
    const int qtp = slot & 7;                  // strip-pair 0..7
    const int h = bh & 15, b = bh >> 4;
    const int tid = threadIdx.x, w = tid >> 6, lane = tid & 63;
    const int cl = lane & 15, lg = lane >> 4;
    const size_t base = (size_t)bh * S * 64;

    __shared__ short Ks[2][64][64];    // K tile [kc][d], XOR-chunk swizzled
    __shared__ short Vt[2][64][72];    // V^T tile [d][kc], padded
    __shared__ short P[8][16][72];     // per-wave P tile [q-local][kc]

    const int krow = lane >> 3;                // staging: wave w -> rows w*8..w*8+7
    const int kchk = (lane & 7) ^ krow;        // inverse-swizzled source chunk
    const int vrow = tid >> 3, vd0 = (tid & 7) * 8;   // V staging

#define STAGEK(BUF, t)                                                            \
    gload_lds16(K + base + (size_t)((t) * 64 + w * 8 + krow) * 64 + kchk * 8,     \
                &Ks[BUF][w * 8][0]);

#define LOADB(BR, t)                                                              \
    { _Pragma("unroll") for (int n = 0; n < 4; ++n)                               \
        BR[n] = *(const sx4*)(bias_bf + (size_t)qr * 2048 + (t) * 64 + n * 16 + (lg << 2)); }

#define LOADV(VR, t)                                                              \
    VR = *(const bx8*)(V + base + (size_t)((t) * 64 + vrow) * 64 + vd0);

#define VSTORE(VR, BUF)                                                           \
    { _Pragma("unroll") for (int j = 0; j < 8; ++j) Vt[BUF][vd0 + j][vrow] = VR[j]; }

#define QKT(BUF, SACC)                                                            \
    { bx8 af0[4], af1[4];                                                         \
      _Pragma("unroll") for (int n = 0; n < 4; ++n) {                             \
        const int row = n * 16 + cl; const int cs = cl & 7;                       \
        af0[n] = *(const bx8*)&Ks[BUF][row][(lg ^ cs) * 8];                       \
        af1[n] = *(const bx8*)&Ks[BUF][row][((4 + lg) ^ cs) * 8]; }               \
      _Pragma("unroll") for (int n = 0; n < 4; ++n) {                             \
        SACC[n] = (fx4){0.f, 0.f, 0.f, 0.f};                                      \
        SACC[n] = MFMA_BF16(af0[n], qf0, SACC[n]);                                \
        SACC[n] = MFMA_BF16(af1[n], qf1, SACC[n]); } }

#define COMP_A(BUF, BR, t)                                                        \
    { fx4 sacc[4]; QKT(BUF, sacc);                                                \
      float sv[4][4]; float tmax = -3.0e38f;                                      \
      _Pragma("unroll") for (int n = 0; n < 4; ++n)                               \
        _Pragma("unroll") for (int r = 0; r < 4; ++r) {                           \
          const int kc = (t) * 64 + n * 16 + (lg << 2) + r;                       \
          sv[n][r] = (kc <= qr) ? (sacc[n][r] + bf2f(BR[n][r])) : -3.0e38f;       \
          tmax = fmaxf(tmax, sv[n][r]); }                                         \
      tmax = fmaxf(tmax, __shfl_xor(tmax, 16));                                   \
      tmax = fmaxf(tmax, __shfl_xor(tmax, 32));                                   \
      const float mnew = fmaxf(m, tmax);                                          \
      float sum = 0.f;                                                            \
      _Pragma("unroll") for (int n = 0; n < 4; ++n)                               \
        _Pragma("unroll") for (int r = 0; r < 4; ++r)                             \
          sum += __expf(sv[n][r] - mnew);                                         \
      sum += __shfl_xor(sum, 16);                                                 \
      sum += __shfl_xor(sum, 32);                                                 \
      l = l * __expf(m - mnew) + sum;                                             \
      m = mnew; }

#define COMP_B(KBUF, BR, VBUF, t)                                                 \
    { fx4 sacc[4]; QKT(KBUF, sacc);                                               \
      float p[4][4];                                                              \
      _Pragma("unroll") for (int n = 0; n < 4; ++n)                               \
        _Pragma("unroll") for (int r = 0; r < 4; ++r) {                           \
          const int kc = (t) * 64 + n * 16 + (lg << 2) + r;                       \
          const float sv = (kc <= qr) ? (sacc[n][r] + bf2f(BR[n][r])) : -3.0e38f; \
          p[n][r] = __expf(sv - m) * invl; }                                      \
      _Pragma("unroll") for (int n = 0; n < 4; ++n) {                             \
        f4v st = (f4v){p[n][0], p[n][1], p[n][2], p[n][3]};                       \
        *(f4v*)(attn_out + arow_base + (t) * 64 + n * 16 + (lg << 2)) = st;       \
        sx4 pb;                                                                   \
        pb[0] = f2bf(p[n][0]); pb[1] = f2bf(p[n][1]);                             \
        pb[2] = f2bf(p[n][2]); pb[3] = f2bf(p[n][3]);                             \
        *(sx4*)&P[w][cl][n * 16 + (lg << 2)] = pb; }                              \
      _Pragma("unroll") for (int kk = 0; kk < 2; ++kk) {                          \
        bx8 pa = *(const bx8*)&P[w][cl][kk * 32 + lg * 8];                        \
        _Pragma("unroll") for (int n = 0; n < 4; ++n) {                           \
          bx8 vb = *(const bx8*)&Vt[VBUF][n * 16 + cl][kk * 32 + lg * 8];         \
          oacc[n] = MFMA_BF16(pa, vb, oacc[n]); } } }

    for (int sidx = 0; sidx < 2; ++sidx) {
        const int qt = sidx ? (15 - qtp) : qtp;     // 128-row strip index
        const int NT = 2 * qt + 2;                  // 64-wide k-tiles (even)

        bx8 qf0, qf1;
        {
            const short* qp = Q + base + (size_t)(qt * 128 + w * 16 + cl) * 64 + lg * 8;
            qf0 = *(const bx8*)qp;
            qf1 = *(const bx8*)(qp + 32);
        }
        const int qr  = qt * 128 + w * 16 + cl;         // lane's q row
        const int sq0 = qt * 128 + w * 16 + (lg << 2);  // lane's first O row
        const size_t arow_base = ((size_t)bh * S + qr) * S;

        float m = -3.0e38f, l = 0.f;
        sx4 bA[4], bB[4];

        // ---- PASS A ----
        STAGEK(0, 0); LOADB(bA, 0);
        __syncthreads();
        for (int t = 0; t < NT; t += 2) {
            STAGEK(1, t + 1); LOADB(bB, t + 1);
            COMP_A(0, bA, t);
            __syncthreads();
            if (t + 2 < NT) { STAGEK(0, t + 2); LOADB(bA, t + 2); }
            COMP_A(1, bB, t + 1);
            __syncthreads();
        }
        const float invl = 1.0f / l;

        fx4 oacc[4];
        #pragma unroll
        for (int n = 0; n < 4; n++) oacc[n] = (fx4){0.f, 0.f, 0.f, 0.f};

        // ---- PASS B ----
        bx8 vrA, vrB;
        STAGEK(0, 0); LOADB(bA, 0); LOADV(vrA, 0);
        __syncthreads();
        VSTORE(vrA, 0);
        __syncthreads();
        for (int t = 0; t < NT; t += 2) {
            STAGEK(1, t + 1); LOADB(bB, t + 1); LOADV(vrB, t + 1);
            COMP_B(0, bA, 0, t);
            VSTORE(vrB, 1);
            __syncthreads();
            if (t + 2 < NT) { STAGEK(0, t + 2); LOADB(bA, t + 2); LOADV(vrA, t + 2); }
            COMP_B(1, bB, 1, t + 1);
            if (t + 2 < NT) VSTORE(vrA, 0);
            __syncthreads();
        }

        // write O tile to o_buf[b][s][h*64+d] (bf16)
        #pragma unroll
        for (int reg = 0; reg < 4; reg++) {
            const int sq = sq0 + reg;
            #pragma unroll
            for (int n = 0; n < 4; n++) {
                const int d = n * 16 + cl;
                o_buf[(size_t)(b * 2048 + sq) * 1024 + h * 64 + d] = f2bf(oacc[n][reg]);
            }
        }

        // zero-fill strict upper triangle (k >= (qt+1)*128) for these 128 q rows
        const int c0 = (qt + 1) * 128;
        if (c0 < S) {
            const int row = tid >> 2;
            float* dst = attn_out + ((size_t)bh * S + qt * 128 + row) * S;
            const f4v z = (f4v){0.f, 0.f, 0.f, 0.f};
            for (int cc = c0 + (tid & 3) * 4; cc < S; cc += 16)
                *(f4v*)(dst + cc) = z;
        }
    }
#undef STAGEK
#undef LOADB
#undef LOADV
#undef VSTORE
#undef QKT
#undef COMP_A
#undef COMP_B
}

extern "C" void kernel_launch(void* const* d_in, const int* in_sizes, int n_in,
                              void* d_out, int out_size, void* d_ws, size_t ws_size,
                              hipStream_t stream) {
    const float* x    = (const float*)d_in[0];
    const float* Wq   = (const float*)d_in[1];
    const float* Wk   = (const float*)d_in[2];
    const float* Wv   = (const float*)d_in[3];
    const float* Wo   = (const float*)d_in[4];
    const float* bias = (const float*)d_in[5];

    float* out  = (float*)d_out;                       // [2,2048,1024] f32
    float* attn = out + (size_t)2 * 2048 * 1024;       // [2,16,2048,2048] f32

    char* ws = (char*)d_ws;
    const size_t M1 = 1u << 20;
    short* x_bf    = (short*)ws;                       // 4M sh (reused as o_buf)
    short* wq_bf   = x_bf + 4 * M1;
    short* wk_bf   = wq_bf + M1;
    short* wv_bf   = wk_bf + M1;
    short* wo_bf   = wv_bf + M1;
    short* bias_bf = wo_bf + M1;                       // 4M sh -> ends at 24MB
    float* cosT    = (float*)(ws + 24 * M1);
    float* sinT    = cosT + 2048 * 64;                 // ends at 25MB
    short* q_rope  = (short*)(ws + 25 * M1);
    short* k_rope  = q_rope + 4 * M1;
    short* v_bf    = k_rope + 4 * M1;                  // ends at 49MB
    short* o_buf   = x_bf;                             // alias (x_bf dead after QKV gemm)

    cast_kernel<<<6144, 256, 0, stream>>>(x, Wq, Wk, Wv, Wo, bias, x_bf);
    rope_table_kernel<<<512, 256, 0, stream>>>(cosT, sinT);
    gemm128<0><<<dim3(32, 8, 3), 256, 0, stream>>>(x_bf, wq_bf, wk_bf, wv_bf,
                                                   cosT, sinT, q_rope);
    attn_kernel<<<256, 512, 0, stream>>>(q_rope, k_rope, v_bf, bias_bf, attn, o_buf);
    gemm128<1><<<dim3(32, 8, 1), 256, 0, stream>>>(o_buf, wo_bf, wo_bf, wo_bf,
                                                   cosT, sinT, out);
}

// Round 7
// 299.974 us; speedup vs baseline: 2.4145x; 1.0656x over previous
//
#include <hip/hip_runtime.h>
#include <hip/hip_bf16.h>
#include <math.h>

// Shapes: B=2, S=2048, H=1024, nh=16, hd=64. Inputs f32, outputs f32.
// d_out = [out: 2*2048*1024] ++ [attn: 2*16*2048*2048], both f32.
// Softmax runs in exp2 domain: q pre-scaled by 0.125*log2e, bias table f32
// pre-scaled by log2e, no running max (scores bounded), l-sum deferred.

typedef __attribute__((ext_vector_type(8))) short bx8;   // 8 bf16 (4 VGPRs)
typedef __attribute__((ext_vector_type(4))) short sx4;   // 4 bf16
typedef __attribute__((ext_vector_type(4))) float fx4;   // MFMA accum
typedef __attribute__((ext_vector_type(4))) float f4v;

#define MFMA_BF16(a, b, c) __builtin_amdgcn_mfma_f32_16x16x32_bf16(a, b, c, 0, 0, 0)
#define LOG2E 1.44269504088896340736f

__device__ __forceinline__ short f2bf(float f) {
    union { float f; unsigned u; } v; v.f = f;
    unsigned u = v.u;
    u += 0x7fffu + ((u >> 16) & 1u);   // RTNE
    return (short)(u >> 16);
}

__device__ __forceinline__ bx8 pack8(f4v a, f4v b) {
    bx8 r;
    r[0] = f2bf(a[0]); r[1] = f2bf(a[1]); r[2] = f2bf(a[2]); r[3] = f2bf(a[3]);
    r[4] = f2bf(b[0]); r[5] = f2bf(b[1]); r[6] = f2bf(b[2]); r[7] = f2bf(b[3]);
    return r;
}

__device__ __forceinline__ void gload_lds16(const short* g, short* l) {
    __builtin_amdgcn_global_load_lds(
        (const __attribute__((address_space(1))) void*)g,
        (__attribute__((address_space(3))) void*)l, 16, 0, 0);
}

// ---------------- cast: blocks 0..4095 -> bf16 of [x:4M][Wq..Wo:4x1M];
//                  blocks 4096..6143 -> biasF = bias * log2e (f32, 4M elems)
__global__ __launch_bounds__(256) void cast_kernel(
        const float* __restrict__ x, const float* __restrict__ Wq,
        const float* __restrict__ Wk, const float* __restrict__ Wv,
        const float* __restrict__ Wo, const float* __restrict__ bias,
        short* __restrict__ dst, float* __restrict__ biasF)
{
    const size_t M1 = 1u << 20;
    if (blockIdx.x < 4096) {
        const size_t e0 = ((size_t)blockIdx.x * 256 + threadIdx.x) * 8;
        const float* src; size_t off;
        if (e0 < 4 * M1) { src = x; off = e0; }
        else {
            const int j = (int)((e0 - 4 * M1) >> 20);
            src = (j == 0) ? Wq : (j == 1) ? Wk : (j == 2) ? Wv : Wo;
            off = (e0 - 4 * M1) & (M1 - 1);
        }
        f4v a = *(const f4v*)(src + off);
        f4v b = *(const f4v*)(src + off + 4);
        *(bx8*)(dst + e0) = pack8(a, b);
    } else {
        const size_t e0 = ((size_t)(blockIdx.x - 4096) * 256 + threadIdx.x) * 8;
        f4v a = *(const f4v*)(bias + e0);
        f4v b = *(const f4v*)(bias + e0 + 4);
        #pragma unroll
        for (int i = 0; i < 4; ++i) { a[i] *= LOG2E; b[i] *= LOG2E; }
        *(f4v*)(biasF + e0) = a;
        *(f4v*)(biasF + e0 + 4) = b;
    }
}

// ---------------- RoPE cos/sin table: [2048][64] f32 each ----------------
__global__ void rope_table_kernel(float* __restrict__ cosT, float* __restrict__ sinT) {
    int i = blockIdx.x * 256 + threadIdx.x;
    if (i >= 2048 * 64) return;
    int s = i >> 6, d = i & 63;
    int fi = d & 31;                               // emb = concat(freqs, freqs)
    float inv_freq = powf(10000.0f, -(float)fi / 32.0f);
    float ang = (float)s * inv_freq;
    cosT[i] = cosf(ang);
    sinT[i] = sinf(ang);
}

// ---------------- GEMM 128x128, BK=64, global_load_lds + XOR chunk swizzle.
// OUTPROJ=0: z in {q,k,v}; RoPE epilogue; q scaled by 0.125*log2e (exp2 fold).
template<int OUTPROJ>
__global__ __launch_bounds__(256) void gemm128(
        const short* __restrict__ A, const short* __restrict__ W0,
        const short* __restrict__ W1, const short* __restrict__ W2,
        const float* __restrict__ cosT, const float* __restrict__ sinT,
        void* __restrict__ Out)
{
    __shared__ short As[128][64];
    __shared__ short Bs[128][64];
    const int bm = blockIdx.x, bn = blockIdx.y, z = blockIdx.z;
    const short* W = OUTPROJ ? W0 : (z == 0 ? W0 : (z == 1 ? W1 : W2));
    const int tid = threadIdx.x, w = tid >> 6, lane = tid & 63;
    const int cl = lane & 15, lg = lane >> 4;
    const int srow = lane >> 3;                 // 0..7 within staged 8-row block
    const int schunk = (lane & 7) ^ srow;       // swizzled global 16B-chunk

    fx4 acc[4][4];
    #pragma unroll
    for (int mi = 0; mi < 4; ++mi)
        #pragma unroll
        for (int ni = 0; ni < 4; ++ni) acc[mi][ni] = (fx4){0.f, 0.f, 0.f, 0.f};

    const int wr = (w >> 1) * 64, wc = (w & 1) * 64;

    for (int k0 = 0; k0 < 1024; k0 += 64) {
        __syncthreads();
        #pragma unroll
        for (int i = 0; i < 4; ++i) {
            const int rbase = w * 32 + i * 8;
            gload_lds16(A + (size_t)(bm * 128 + rbase + srow) * 1024 + k0 + schunk * 8,
                        &As[rbase][0]);
            gload_lds16(W + (size_t)(bn * 128 + rbase + srow) * 1024 + k0 + schunk * 8,
                        &Bs[rbase][0]);
        }
        __syncthreads();
        #pragma unroll
        for (int kk = 0; kk < 2; ++kk) {
            bx8 af[4], bf[4];
            #pragma unroll
            for (int i = 0; i < 4; ++i) {
                const int ra = wr + i * 16 + cl;
                af[i] = *(const bx8*)&As[ra][((kk * 4 + lg) ^ (ra & 7)) * 8];
                const int rb = wc + i * 16 + cl;
                bf[i] = *(const bx8*)&Bs[rb][((kk * 4 + lg) ^ (rb & 7)) * 8];
            }
            #pragma unroll
            for (int mi = 0; mi < 4; ++mi)
                #pragma unroll
                for (int ni = 0; ni < 4; ++ni)
                    acc[mi][ni] = MFMA_BF16(af[mi], bf[ni], acc[mi][ni]);
        }
    }

    #pragma unroll
    for (int mi = 0; mi < 4; ++mi) {
        #pragma unroll
        for (int reg = 0; reg < 4; ++reg) {
            const int r = bm * 128 + wr + mi * 16 + (lg << 2) + reg;
            if constexpr (OUTPROJ) {
                #pragma unroll
                for (int ni = 0; ni < 4; ++ni) {
                    const int col = bn * 128 + wc + ni * 16 + cl;
                    ((float*)Out)[(size_t)r * 1024 + col] = acc[mi][ni][reg];
                }
            } else {
                const int b = r >> 11, s = r & 2047;
                const int h = bn * 2 + (wc >> 6);
                short* dst = (short*)Out + (size_t)z * 32 * 2048 * 64
                           + (size_t)((b * 16 + h) * 2048 + s) * 64;
                #pragma unroll
                for (int ni = 0; ni < 4; ++ni) {
                    const int d = ni * 16 + cl;
                    float v = acc[mi][ni][reg];
                    if (z <= 1) {
                        const float cs = cosT[s * 64 + d], sn = sinT[s * 64 + d];
                        const float partner = acc[mi][ni ^ 2][reg];   // d ^ 32
                        const float rot = (d < 32) ? -partner : partner;
                        v = v * cs + rot * sn;
                        if (z == 0) v *= 0.125f * LOG2E;   // scale+exp2 fold into q
                    }
                    dst[d] = f2bf(v);
                }
            }
        }
    }
}

// ---------------- Attention: 256 thr (4 waves x 16 q-rows), grid 1024
// (32 qt x 32 bh, qt descending, 4 bh per XCD co-resident). No running max:
// pass A accumulates l = sum exp2(s2) with NO per-tile cross-lane ops; one
// 2-shuffle reduce at end. Bias rides as MFMA C-operand (biasF = bias*log2e).
// Pass B: p = exp2(s2 - log2(l)). K staged via gload_lds+XOR (dbuf); V
// reg->LDS transposed (dbuf); P LDS round-trip for PV MFMA.
__global__ __launch_bounds__(256, 3) void attn_kernel(
        const short* __restrict__ Q, const short* __restrict__ K,
        const short* __restrict__ V, const float* __restrict__ biasF,
        float* __restrict__ attn_out, short* __restrict__ o_buf)
{
    const int S = 2048;
    const int bid = blockIdx.x;
    const int xcd = bid & 7, rr_ = bid >> 3;       // XCD-local decode
    const int bh = xcd * 4 + (rr_ & 3);            // 4 (b,h) per XCD
    const int qt = 31 - (rr_ >> 2);                // big strips first
    const int h = bh & 15, b = bh >> 4;
    const int tid = threadIdx.x, w = tid >> 6, lane = tid & 63;
    const int cl = lane & 15, lg = lane >> 4;
    const size_t base = (size_t)bh * S * 64;
    const int NT = qt + 1;

    __shared__ short Ks[2][64][64];    // K tile [kc][d], XOR-chunk swizzled
    __shared__ short Vt[2][64][72];    // V^T tile [d][kc]
    __shared__ short P[4][16][72];     // per-wave P tile

    const int krow8 = lane >> 3, kchk = (lane & 7) ^ krow8;
    const int vrow = tid >> 2, vd0 = (tid & 3) * 16;

    const short* qp = Q + base + (size_t)(qt * 64 + w * 16 + cl) * 64 + lg * 8;
    const bx8 qf0 = *(const bx8*)qp;
    const bx8 qf1 = *(const bx8*)(qp + 32);
    const int qr  = qt * 64 + w * 16 + cl;          // lane's q row
    const int sq0 = qt * 64 + w * 16 + (lg << 2);   // lane's first O row
    const float* brow = biasF + (size_t)qr * 2048;
    const size_t arow_base = ((size_t)bh * S + qr) * S;

#define STAGEK(BUF, t)                                                            \
    { gload_lds16(K + base + (size_t)((t) * 64 + w * 16 + krow8) * 64 + kchk * 8, \
                  &Ks[BUF][w * 16][0]);                                           \
      gload_lds16(K + base + (size_t)((t) * 64 + w * 16 + 8 + krow8) * 64 + kchk * 8, \
                  &Ks[BUF][w * 16 + 8][0]); }

#define LOADB(BR, t)                                                              \
    { _Pragma("unroll") for (int n = 0; n < 4; ++n)                               \
        BR[n] = *(const f4v*)(brow + (t) * 64 + n * 16 + (lg << 2)); }

#define QKT(BUF, BR, SACC)                                                        \
    { const int cs_ = cl & 7;                                                     \
      _Pragma("unroll") for (int n = 0; n < 4; ++n) {                             \
        bx8 a0 = *(const bx8*)&Ks[BUF][n * 16 + cl][(lg ^ cs_) * 8];              \
        bx8 a1 = *(const bx8*)&Ks[BUF][n * 16 + cl][((4 + lg) ^ cs_) * 8];        \
        SACC[n] = MFMA_BF16(a0, qf0, BR[n]);                                      \
        SACC[n] = MFMA_BF16(a1, qf1, SACC[n]); } }

#define COMP_A(BUF, BR, t)                                                        \
    { fx4 sacc[4]; QKT(BUF, BR, sacc);                                            \
      _Pragma("unroll") for (int n = 0; n < 4; ++n)                               \
        _Pragma("unroll") for (int e = 0; e < 4; ++e) {                           \
          const int kc = (t) * 64 + n * 16 + (lg << 2) + e;                       \
          lsum[n] += (kc <= qr) ? exp2f(sacc[n][e]) : 0.f; } }

#define LOADVr(V0, V1, t)                                                         \
    { const short* vp = V + base + (size_t)((t) * 64 + vrow) * 64 + vd0;          \
      V0 = *(const bx8*)vp; V1 = *(const bx8*)(vp + 8); }

#define VSTORE(V0, V1, BUF)                                                       \
    { _Pragma("unroll") for (int j = 0; j < 8; ++j) Vt[BUF][vd0 + j][vrow] = V0[j]; \
      _Pragma("unroll") for (int j = 0; j < 8; ++j) Vt[BUF][vd0 + 8 + j][vrow] = V1[j]; }

#define COMP_B(KBUF, BR, VBUF, t)                                                 \
    { fx4 sacc[4]; QKT(KBUF, BR, sacc);                                           \
      float p[4][4];                                                              \
      _Pragma("unroll") for (int n = 0; n < 4; ++n)                               \
        _Pragma("unroll") for (int e = 0; e < 4; ++e) {                           \
          const int kc = (t) * 64 + n * 16 + (lg << 2) + e;                       \
          p[n][e] = (kc <= qr) ? exp2f(sacc[n][e] - L2) : 0.f; }                  \
      _Pragma("unroll") for (int n = 0; n < 4; ++n) {                             \
        f4v st = (f4v){p[n][0], p[n][1], p[n][2], p[n][3]};                       \
        *(f4v*)(attn_out + arow_base + (t) * 64 + n * 16 + (lg << 2)) = st;       \
        sx4 pb;                                                                   \
        pb[0] = f2bf(p[n][0]); pb[1] = f2bf(p[n][1]);                             \
        pb[2] = f2bf(p[n][2]); pb[3] = f2bf(p[n][3]);                             \
        *(sx4*)&P[w][cl][n * 16 + (lg << 2)] = pb; }                              \
      _Pragma("unroll") for (int kk = 0; kk < 2; ++kk) {                          \
        bx8 pa = *(const bx8*)&P[w][cl][kk * 32 + lg * 8];                        \
        _Pragma("unroll") for (int n = 0; n < 4; ++n) {                           \
          bx8 vb = *(const bx8*)&Vt[VBUF][n * 16 + cl][kk * 32 + lg * 8];         \
          oacc[n] = MFMA_BF16(pa, vb, oacc[n]); } } }

    float lsum[4] = {0.f, 0.f, 0.f, 0.f};
    f4v bA[4], bB[4];

    // ---- PASS A: l = sum exp2(s2); no per-tile cross-lane ops ----
    STAGEK(0, 0); LOADB(bA, 0);
    __syncthreads();
    int t = 0;
    for (; t + 1 < NT; t += 2) {
        STAGEK(1, t + 1); LOADB(bB, t + 1);
        COMP_A(0, bA, t);
        __syncthreads();
        if (t + 2 < NT) { STAGEK(0, t + 2); LOADB(bA, t + 2); }
        COMP_A(1, bB, t + 1);
        __syncthreads();
    }
    if (t < NT) COMP_A(0, bA, t);

    float l = (lsum[0] + lsum[1]) + (lsum[2] + lsum[3]);
    l += __shfl_xor(l, 16);
    l += __shfl_xor(l, 32);
    const float L2 = __log2f(l);

    fx4 oacc[4];
    #pragma unroll
    for (int n = 0; n < 4; n++) oacc[n] = (fx4){0.f, 0.f, 0.f, 0.f};

    // ---- PASS B ----
    bx8 vA0, vA1, vB0, vB1;
    __syncthreads();                   // pass A Ks readers done
    STAGEK(0, 0); LOADB(bA, 0); LOADVr(vA0, vA1, 0);
    __syncthreads();                   // Ks[0] staged
    VSTORE(vA0, vA1, 0);
    __syncthreads();                   // Vt[0] visible
    t = 0;
    for (; t + 1 < NT; t += 2) {
        STAGEK(1, t + 1); LOADB(bB, t + 1); LOADVr(vB0, vB1, t + 1);
        COMP_B(0, bA, 0, t);
        VSTORE(vB0, vB1, 1);
        __syncthreads();
        if (t + 2 < NT) { STAGEK(0, t + 2); LOADB(bA, t + 2); LOADVr(vA0, vA1, t + 2); }
        COMP_B(1, bB, 1, t + 1);
        if (t + 2 < NT) VSTORE(vA0, vA1, 0);
        __syncthreads();
    }
    if (t < NT) COMP_B(0, bA, 0, t);

    // write O tile to o_buf[b][s][h*64+d] (bf16)
    #pragma unroll
    for (int reg = 0; reg < 4; reg++) {
        const int sq = sq0 + reg;
        #pragma unroll
        for (int n = 0; n < 4; n++) {
            const int d = n * 16 + cl;
            o_buf[(size_t)(b * 2048 + sq) * 1024 + h * 64 + d] = f2bf(oacc[n][reg]);
        }
    }

    // zero-fill strict upper triangle (k >= (qt+1)*64) for these 64 q rows
    const int c0 = (qt + 1) * 64;
    if (c0 < S) {
        const int row = tid >> 2;
        float* dst = attn_out + ((size_t)bh * S + qt * 64 + (row & 63)) * S;
        const f4v z = (f4v){0.f, 0.f, 0.f, 0.f};
        for (int cc = c0 + (tid & 3) * 4; cc < S; cc += 16)
            *(f4v*)(dst + cc) = z;
    }
#undef STAGEK
#undef LOADB
#undef QKT
#undef COMP_A
#undef LOADVr
#undef VSTORE
#undef COMP_B
}

extern "C" void kernel_launch(void* const* d_in, const int* in_sizes, int n_in,
                              void* d_out, int out_size, void* d_ws, size_t ws_size,
                              hipStream_t stream) {
    const float* x    = (const float*)d_in[0];
    const float* Wq   = (const float*)d_in[1];
    const float* Wk   = (const float*)d_in[2];
    const float* Wv   = (const float*)d_in[3];
    const float* Wo   = (const float*)d_in[4];
    const float* bias = (const float*)d_in[5];

    float* out  = (float*)d_out;                       // [2,2048,1024] f32
    float* attn = out + (size_t)2 * 2048 * 1024;       // [2,16,2048,2048] f32

    char* ws = (char*)d_ws;
    const size_t M1 = 1u << 20;
    short* x_bf    = (short*)ws;                       // 4M sh (reused as o_buf)
    short* wq_bf   = x_bf + 4 * M1;
    short* wk_bf   = wq_bf + M1;
    short* wv_bf   = wk_bf + M1;
    short* wo_bf   = wv_bf + M1;                       // bf16 region ends 16MB
    float* biasF   = (float*)(ws + 16 * M1);           // 4M f32 -> ends 32MB
    float* cosT    = (float*)(ws + 32 * M1);
    float* sinT    = cosT + 2048 * 64;                 // ends 33MB
    short* q_rope  = (short*)(ws + 33 * M1);
    short* k_rope  = q_rope + 4 * M1;
    short* v_bf    = k_rope + 4 * M1;                  // ends 57MB
    short* o_buf   = x_bf;                             // alias (x_bf dead after QKV)

    cast_kernel<<<6144, 256, 0, stream>>>(x, Wq, Wk, Wv, Wo, bias, x_bf, biasF);
    rope_table_kernel<<<512, 256, 0, stream>>>(cosT, sinT);
    gemm128<0><<<dim3(32, 8, 3), 256, 0, stream>>>(x_bf, wq_bf, wk_bf, wv_bf,
                                                   cosT, sinT, q_rope);
    attn_kernel<<<1024, 256, 0, stream>>>(q_rope, k_rope, v_bf, biasF, attn, o_buf);
    gemm128<1><<<dim3(32, 8, 1), 256, 0, stream>>>(o_buf, wo_bf, wo_bf, wo_bf,
                                                   cosT, sinT, out);
}